// Round 9
// baseline (850.031 us; speedup 1.0000x reference)
//
#include <hip/hip_runtime.h>
#include <cstddef>
#include <cstdint>

#define BN_EPS 1e-5f

typedef float f4 __attribute__((ext_vector_type(4)));
typedef float f32x4 __attribute__((ext_vector_type(4)));
typedef _Float16 h2 __attribute__((ext_vector_type(2)));
typedef _Float16 h8 __attribute__((ext_vector_type(8)));

#if defined(__has_builtin)
#if __has_builtin(__builtin_amdgcn_fdot2)
#define DOT2(a, b, c) __builtin_amdgcn_fdot2((a), (b), (c), false)
#endif
#endif
#ifndef DOT2
#define DOT2(a, b, c) fmaf((float)(a)[1], (float)(b)[1], fmaf((float)(a)[0], (float)(b)[0], (c)))
#endif

// ---------------------------------------------------------------------------
// f16 weight transpose (sconv_r1): W[27][CIN][COUT] -> Wh[k][ci/8][co][8]
// ---------------------------------------------------------------------------
template<int CIN, int COUT>
__global__ __launch_bounds__(256)
void wtrans_h(const float* __restrict__ W, _Float16* __restrict__ Wh)
{
    const int t = blockIdx.x * 256 + threadIdx.x;
    constexpr int TOTAL = 27 * (CIN / 8) * COUT;
    if (t >= TOTAL) return;
    const int co = t % COUT;
    const int rest = t / COUT;
    const int t8 = rest % (CIN / 8);
    const int k  = rest / (CIN / 8);
    h8 v;
    #pragma unroll
    for (int u = 0; u < 8; ++u)
        v[u] = (_Float16)W[((size_t)k * CIN + t8 * 8 + u) * COUT + co];
    *(h8*)(Wh + (size_t)t * 8) = v;
}

// ---------------------------------------------------------------------------
// MFMA weight transform: W[27][CIN][COUT] fp32 -> B-fragment layout f16:
// Wm[((k*NT + t)*NC + ct)*64 + lane][8], h8 holds B[kk][co] with
// kk = t*32 + (lane>>4)*8 + u, co = ct*16 + (lane&15).
// ---------------------------------------------------------------------------
template<int CIN, int COUT>
__global__ __launch_bounds__(256)
void wtrans_mf(const float* __restrict__ W, _Float16* __restrict__ Wm)
{
    constexpr int NT = CIN / 32;
    constexpr int NC = COUT / 16;
    const int t = blockIdx.x * 256 + threadIdx.x;
    constexpr int TOTAL = 27 * NT * NC * 64;
    if (t >= TOTAL) return;
    const int lane = t & 63;
    int rest = t >> 6;
    const int ct = rest % NC; rest /= NC;
    const int tt = rest % NT;
    const int k  = rest / NT;
    const int cin0 = tt * 32 + (lane >> 4) * 8;
    const int co   = ct * 16 + (lane & 15);
    h8 v;
    #pragma unroll
    for (int u = 0; u < 8; ++u)
        v[u] = (_Float16)W[((size_t)k * CIN + cin0 + u) * COUT + co];
    *(h8*)(Wm + (size_t)t * 8) = v;
}

// ---------------------------------------------------------------------------
// conv0 MFMA weight transform (CIN=16, COUT=32, k-PAIRED):
// Wm0[((k*2 + s)*32 + co)*8 + u] = f16(W0[k][s*8+u][co]).
// ---------------------------------------------------------------------------
__global__ __launch_bounds__(256)
void wtrans_mf0(const float* __restrict__ W, _Float16* __restrict__ Wm0)
{
    const int t = blockIdx.x * 256 + threadIdx.x;
    constexpr int TOTAL = 27 * 2 * 32;
    if (t >= TOTAL) return;
    const int co = t % 32;
    const int s  = (t / 32) % 2;
    const int k  = t / 64;
    h8 v;
    #pragma unroll
    for (int u = 0; u < 8; ++u)
        v[u] = (_Float16)W[((size_t)k * 16 + s * 8 + u) * 32 + co];
    *(h8*)(Wm0 + (size_t)t * 8) = v;
}

// ---------------------------------------------------------------------------
// Map transpose: map[27][Nout] -> mapT[Nout][32] (k-major per row, -1 pad).
// ---------------------------------------------------------------------------
__global__ __launch_bounds__(256)
void map_transpose(const int* __restrict__ map, int Nout,
                   int* __restrict__ mapT)
{
    __shared__ int s[256][28];
    const int tid  = threadIdx.x;
    const int base = blockIdx.x * 256;
    const int j    = base + tid;
    for (int k = 0; k < 27; ++k)
        s[tid][k] = (j < Nout) ? map[(size_t)k * Nout + j] : -1;
    __syncthreads();
    for (int i = tid; i < 256 * 32; i += 256) {
        const int r = i >> 5, c = i & 31;
        if (base + r < Nout)
            mapT[(size_t)(base + r) * 32 + c] = (c < 27) ? s[r][c] : -1;
    }
}

// ---------------------------------------------------------------------------
// Map transpose + parity-class GROUPING, contention-free: LDS histogram ->
// 9 global atomics PER BLOCK -> LDS cursors. Class regions fixed at c*Npad
// in order[] (unfilled slots stay -1, pre-memset 0xFF). Perf heuristic only.
// ---------------------------------------------------------------------------
__global__ __launch_bounds__(256)
void map_transpose_grp(const int* __restrict__ map, int Nout, int Npad,
                       int* __restrict__ mapT, int* __restrict__ gcursor,
                       int* __restrict__ order)
{
    __shared__ int s[256][28];
    __shared__ int hist[9], basec[9], cur[9];
    const int tid  = threadIdx.x;
    const int base = blockIdx.x * 256;
    const int j    = base + tid;
    if (tid < 9) { hist[tid] = 0; cur[tid] = 0; }
    for (int k = 0; k < 27; ++k)
        s[tid][k] = (j < Nout) ? map[(size_t)k * Nout + j] : -1;
    __syncthreads();
    for (int i = tid; i < 256 * 32; i += 256) {
        const int r = i >> 5, c = i & 31;
        if (base + r < Nout)
            mapT[(size_t)(base + r) * 32 + c] = (c < 27) ? s[r][c] : -1;
    }
    int c9 = 8;
    if (j < Nout) {
        #pragma unroll 1
        for (int k = 0; k < 27; ++k) {
            if (s[tid][k] >= 0) {
                const int dz = k % 3, dy = (k / 3) % 3, dx = k / 9;
                c9 = ((dx != 1) << 2) | ((dy != 1) << 1) | (int)(dz != 1);
                break;
            }
        }
        atomicAdd(&hist[c9], 1);
    }
    __syncthreads();
    if (tid < 9 && hist[tid] > 0)
        basec[tid] = atomicAdd(&gcursor[tid], hist[tid]);
    __syncthreads();
    if (j < Nout) {
        const int lpos = atomicAdd(&cur[c9], 1);
        order[(size_t)c9 * Npad + basec[c9] + lpos] = j;
    }
}

// ---------------------------------------------------------------------------
// R=1 f16 sparse conv (SPARSE maps): one wave = one row. (block1)
// ---------------------------------------------------------------------------
template<int CIN, int CINA, int COUT>
__global__ __launch_bounds__(256)
void sconv_r1(const _Float16* __restrict__ xA, const _Float16* __restrict__ xB,
              const _Float16* __restrict__ Wh, const int* __restrict__ mapT,
              int Nout, _Float16* __restrict__ out)
{
    constexpr int CINB = CIN - CINA;
    constexpr int CPL  = COUT / 64;
    constexpr int NT   = CIN / 8;
    const int lane = threadIdx.x & 63;
    const int j    = blockIdx.x * 4 + (threadIdx.x >> 6);

    int mk = -1;
    if (j < Nout && lane < 32) mk = mapT[(size_t)j * 32 + lane];
    unsigned long long act = __ballot(mk >= 0);   // bits 0..26 only

    float acc[CPL];
    #pragma unroll
    for (int c = 0; c < CPL; ++c) acc[c] = 0.f;

    while (act) {
        const int k = (int)__builtin_ctzll(act);
        act &= act - 1;
        const int m = __builtin_amdgcn_readlane(mk, k);   // uniform SGPR

        const _Float16* pA = xA + (size_t)m * CINA;
        const _Float16* pB = nullptr;
        if constexpr (CINB > 0) pB = xB + (size_t)m * CINB;

        const _Float16* Wk = Wh + (size_t)k * NT * COUT * 8;

        #pragma unroll
        for (int t = 0; t < NT; ++t) {
            const int ci = t * 8;
            h8 wv[CPL];
            #pragma unroll
            for (int c = 0; c < CPL; ++c)
                wv[c] = *(const h8*)(Wk + ((size_t)t * COUT + c * 64 + lane) * 8);
            const _Float16* p;
            if constexpr (CINB > 0)
                p = (ci < CINA) ? (pA + ci) : (pB + (ci - CINA));
            else
                p = pA + ci;
            const h8 xv = *(const h8*)p;
            const h2* xp = (const h2*)&xv;
            #pragma unroll
            for (int q = 0; q < 4; ++q) {
                #pragma unroll
                for (int c = 0; c < CPL; ++c) {
                    const h2* wp = (const h2*)&wv[c];
                    acc[c] = DOT2(xp[q], wp[q], acc[c]);
                }
            }
        }
    }

    if (j < Nout) {
        #pragma unroll
        for (int c = 0; c < CPL; ++c)
            out[(size_t)j * COUT + c * 64 + lane] = (_Float16)acc[c];
    }
}

// ---------------------------------------------------------------------------
// conv0 MFMA (CIN=16 fp32 in, COUT=32, k-PAIRED, compensated hi/lo).
// ---------------------------------------------------------------------------
__global__ __launch_bounds__(256)
void sconv_mf0(const float* __restrict__ x, const _Float16* __restrict__ Wm0,
               const int* __restrict__ map, int Nout,
               _Float16* __restrict__ out, const float* __restrict__ zrow)
{
    const int lane = threadIdx.x & 63;
    const int wave = threadIdx.x >> 6;
    const int row0 = (blockIdx.x * 4 + wave) * 16;

    __shared__ int smap[4][16][28];

    int mk[16];
    bool anyv = false;
    #pragma unroll
    for (int r = 0; r < 16; ++r) {
        const int j = row0 + r;
        mk[r] = (lane < 27 && j < Nout) ? map[(size_t)lane * Nout + j] : -1;
        anyv |= (mk[r] >= 0);
    }
    unsigned long long act = __ballot(anyv);

    if (lane < 27) {
        #pragma unroll
        for (int r = 0; r < 16; ++r)
            smap[wave][r][lane] = mk[r];
    }

    f32x4 accH[2], accL[2];
    #pragma unroll
    for (int c = 0; c < 2; ++c) {
        accH[c] = (f32x4){0.f, 0.f, 0.f, 0.f};
        accL[c] = (f32x4){0.f, 0.f, 0.f, 0.f};
    }

    const int rrow = lane & 15;   // A row / D col
    const int kseg = lane >> 4;
    const int half = kseg & 1;    // cin half: 0 -> 0..7, 1 -> 8..15
    const bool useK1 = (kseg < 2);

    while (act) {
        const int k1 = (int)__builtin_ctzll(act);
        act &= act - 1;
        int k2 = -1;
        if (act) {
            k2 = (int)__builtin_ctzll(act);
            act &= act - 1;
        }
        const int ks = useK1 ? k1 : k2;
        int m = -1;
        if (ks >= 0) m = smap[wave][rrow][ks];

        const float* px = (m >= 0) ? (x + (size_t)m * 16 + half * 8)
                                   : (zrow + half * 8);
        const f4 x0 = *(const f4*)px;
        const f4 x1 = *(const f4*)(px + 4);
        h8 aH, aL;
        #pragma unroll
        for (int u = 0; u < 4; ++u) {
            const float v0 = x0[u], v1 = x1[u];
            const _Float16 h0 = (_Float16)v0;
            const _Float16 h1 = (_Float16)v1;
            aH[u]     = h0;
            aH[u + 4] = h1;
            aL[u]     = (_Float16)((v0 - (float)h0) * 2048.f);
            aL[u + 4] = (_Float16)((v1 - (float)h1) * 2048.f);
        }

        const int ksafe = (ks >= 0) ? ks : 0;   // a==0 makes b irrelevant
        const _Float16* wb = Wm0 + ((size_t)(ksafe * 2 + half) * 32) * 8;
        #pragma unroll
        for (int c = 0; c < 2; ++c) {
            const h8 b = *(const h8*)(wb + (size_t)(c * 16 + rrow) * 8);
            accH[c] = __builtin_amdgcn_mfma_f32_16x16x32_f16(aH, b, accH[c], 0, 0, 0);
            accL[c] = __builtin_amdgcn_mfma_f32_16x16x32_f16(aL, b, accL[c], 0, 0, 0);
        }
    }

    #pragma unroll
    for (int c = 0; c < 2; ++c) {
        #pragma unroll
        for (int r = 0; r < 4; ++r) {
            const int j = row0 + kseg * 4 + r;
            if (j < Nout)
                out[(size_t)j * 32 + c * 16 + rrow] =
                    (_Float16)(accH[c][r] + accL[c][r] * (1.f / 2048.f));
        }
    }
}

// ---------------------------------------------------------------------------
// MFMA sparse conv (UNGROUPED, raw map): one wave = 32 rows = TWO 16-row
// MFMA tiles sharing one k-union and the SAME B fragments. (block2)
// ---------------------------------------------------------------------------
template<int CIN, int CINA, int COUT>
__global__ __launch_bounds__(256)
void sconv_mf(const _Float16* __restrict__ xA, const _Float16* __restrict__ xB,
              const _Float16* __restrict__ Wm, const int* __restrict__ map,
              int Nout, _Float16* __restrict__ out,
              const _Float16* __restrict__ zrh)
{
    constexpr int CINB = CIN - CINA;
    constexpr int NT = CIN / 32;
    constexpr int NC = COUT / 16;
    static_assert(CINA % 32 == 0, "CINA must be a multiple of 32");
    const int lane = threadIdx.x & 63;
    const int wave = threadIdx.x >> 6;
    const int row0 = (blockIdx.x * 4 + wave) * 32;

    __shared__ int smap[4][32][28];

    bool anyv = false;
    #pragma unroll
    for (int r = 0; r < 32; ++r) {
        const int j = row0 + r;
        const int v = (lane < 27 && j < Nout) ? map[(size_t)lane * Nout + j] : -1;
        if (lane < 27) smap[wave][r][lane] = v;
        anyv |= (v >= 0);
    }
    unsigned long long act = __ballot(anyv) & 0x7FFFFFFull;

    f32x4 acc[2][NC];
    #pragma unroll
    for (int tt = 0; tt < 2; ++tt)
        #pragma unroll
        for (int c = 0; c < NC; ++c) acc[tt][c] = (f32x4){0.f, 0.f, 0.f, 0.f};

    const int rrow = lane & 15;
    const int kseg = lane >> 4;

    auto loada = [&](int k, h8 a[2][NT]) {
        #pragma unroll
        for (int tt = 0; tt < 2; ++tt) {
            const int m = smap[wave][tt * 16 + rrow][k];
            #pragma unroll
            for (int t = 0; t < NT; ++t) {
                const int cin0 = t * 32 + kseg * 8;
                const _Float16* pa;
                if (m >= 0) {
                    if (CINB > 0 && t * 32 >= CINA)
                        pa = xB + (size_t)m * CINB + (cin0 - CINA);
                    else
                        pa = xA + (size_t)m * CINA + cin0;
                } else {
                    pa = zrh;
                }
                a[tt][t] = *(const h8*)pa;
            }
        }
    };
    auto compute = [&](int k, h8 a[2][NT]) {
        const _Float16* Wk = Wm + ((size_t)k * NT * NC * 64 + lane) * 8;
        #pragma unroll
        for (int t = 0; t < NT; ++t) {
            #pragma unroll
            for (int c = 0; c < NC; ++c) {
                const h8 b = *(const h8*)(Wk + (size_t)(t * NC + c) * 64 * 8);
                acc[0][c] = __builtin_amdgcn_mfma_f32_16x16x32_f16(a[0][t], b, acc[0][c], 0, 0, 0);
                acc[1][c] = __builtin_amdgcn_mfma_f32_16x16x32_f16(a[1][t], b, acc[1][c], 0, 0, 0);
            }
        }
    };

    h8 aC[2][NT], aN[2][NT];
    int kC = -1;
    if (act) {
        kC = (int)__builtin_ctzll(act);
        act &= act - 1;
        loada(kC, aC);
    }
    while (kC >= 0) {
        int kN = -1;
        if (act) {
            kN = (int)__builtin_ctzll(act);
            act &= act - 1;
            loada(kN, aN);
        }
        compute(kC, aC);
        #pragma unroll
        for (int tt = 0; tt < 2; ++tt)
            #pragma unroll
            for (int t = 0; t < NT; ++t) aC[tt][t] = aN[tt][t];
        kC = kN;
    }

    #pragma unroll
    for (int tt = 0; tt < 2; ++tt) {
        #pragma unroll
        for (int c = 0; c < NC; ++c) {
            #pragma unroll
            for (int r = 0; r < 4; ++r) {
                const int j = row0 + tt * 16 + kseg * 4 + r;
                if (j < Nout)
                    out[(size_t)j * COUT + c * 16 + rrow] = (_Float16)acc[tt][c][r];
            }
        }
    }
}

// ---------------------------------------------------------------------------
// MFMA sparse conv (GROUPED): 32 order slots/wave, two 16-row MFMA tiles
// sharing the class k-union and B fragments. Dead waves exit early.
// ---------------------------------------------------------------------------
template<int CIN, int CINA, int COUT>
__global__ __launch_bounds__(256)
void sconv_mf_g(const _Float16* __restrict__ xA, const _Float16* __restrict__ xB,
                const _Float16* __restrict__ Wm, const int* __restrict__ mapT,
                const int* __restrict__ order, int NTOT, int Nout,
                _Float16* __restrict__ out, const _Float16* __restrict__ zrh)
{
    constexpr int CINB = CIN - CINA;
    constexpr int NT = CIN / 32;
    constexpr int NC = COUT / 16;
    static_assert(CINA % 32 == 0, "CINA must be a multiple of 32");
    const int lane = threadIdx.x & 63;
    const int wave = threadIdx.x >> 6;
    const int wrow0 = (blockIdx.x * 4 + wave) * 32;

    __shared__ int sjr[4][32];
    __shared__ int smap[4][32][28];

    int jreg = -1;
    if (lane < 32) {
        const int idx = wrow0 + lane;
        if (idx < NTOT) jreg = order[idx];
    }
    if (!__ballot(jreg >= 0)) return;     // dead wave: region tail padding
    if (lane < 32) sjr[wave][lane] = jreg;

    bool anyv = false;
    #pragma unroll
    for (int r = 0; r < 32; ++r) {
        const int jr = sjr[wave][r];      // wave-local LDS RAW (lgkmcnt)
        int v = -1;
        if (jr >= 0 && lane < 27) v = mapT[(size_t)jr * 32 + lane];
        if (lane < 27) smap[wave][r][lane] = v;
        anyv |= (v >= 0);
    }
    unsigned long long act = __ballot(anyv) & 0x7FFFFFFull;

    f32x4 acc[2][NC];
    #pragma unroll
    for (int tt = 0; tt < 2; ++tt)
        #pragma unroll
        for (int c = 0; c < NC; ++c) acc[tt][c] = (f32x4){0.f, 0.f, 0.f, 0.f};

    const int rrow = lane & 15;
    const int kseg = lane >> 4;

    auto loada = [&](int k, h8 a[2][NT]) {
        #pragma unroll
        for (int tt = 0; tt < 2; ++tt) {
            const int m = smap[wave][tt * 16 + rrow][k];
            #pragma unroll
            for (int t = 0; t < NT; ++t) {
                const int cin0 = t * 32 + kseg * 8;
                const _Float16* pa;
                if (m >= 0) {
                    if (CINB > 0 && t * 32 >= CINA)
                        pa = xB + (size_t)m * CINB + (cin0 - CINA);
                    else
                        pa = xA + (size_t)m * CINA + cin0;
                } else {
                    pa = zrh;
                }
                a[tt][t] = *(const h8*)pa;
            }
        }
    };
    auto compute = [&](int k, h8 a[2][NT]) {
        const _Float16* Wk = Wm + ((size_t)k * NT * NC * 64 + lane) * 8;
        #pragma unroll
        for (int t = 0; t < NT; ++t) {
            #pragma unroll
            for (int c = 0; c < NC; ++c) {
                const h8 b = *(const h8*)(Wk + (size_t)(t * NC + c) * 64 * 8);
                acc[0][c] = __builtin_amdgcn_mfma_f32_16x16x32_f16(a[0][t], b, acc[0][c], 0, 0, 0);
                acc[1][c] = __builtin_amdgcn_mfma_f32_16x16x32_f16(a[1][t], b, acc[1][c], 0, 0, 0);
            }
        }
    };

    h8 aC[2][NT], aN[2][NT];
    int kC = -1;
    if (act) {
        kC = (int)__builtin_ctzll(act);
        act &= act - 1;
        loada(kC, aC);
    }
    while (kC >= 0) {
        int kN = -1;
        if (act) {
            kN = (int)__builtin_ctzll(act);
            act &= act - 1;
            loada(kN, aN);
        }
        compute(kC, aC);
        #pragma unroll
        for (int tt = 0; tt < 2; ++tt)
            #pragma unroll
            for (int t = 0; t < NT; ++t) aC[tt][t] = aN[tt][t];
        kC = kN;
    }

    #pragma unroll
    for (int tt = 0; tt < 2; ++tt) {
        #pragma unroll
        for (int c = 0; c < NC; ++c) {
            #pragma unroll
            for (int r = 0; r < 4; ++r) {
                const int j = sjr[wave][tt * 16 + kseg * 4 + r];
                if (j >= 0)
                    out[(size_t)j * COUT + c * 16 + rrow] = (_Float16)acc[tt][c][r];
            }
        }
    }
}

// ---------------------------------------------------------------------------
// conv0t SCATTER (round-9): the stride-1 map is self-inverse under k->26-k
// (map[k][j]=m <=> map[26-k][m]=j, both sides on c0). So instead of output j
// random-GATHERING ~3.4 neighbor rows (192B each, random -> 92MB HBM at poor
// efficiency = the whole 75us), input row i STREAMS its x once (coalesced)
// and scatter-adds x[i]*W[26-k] into out[map[k][i]] with 2 fp32 atomics per
// active k. 1.36M atomics over 400k addresses (~3.4 contention) is trivial.
// out must be pre-zeroed. Paired-lane reduce: 6 shfl for both sums.
// ---------------------------------------------------------------------------
__global__ __launch_bounds__(256)
void sconv0t_scatter(const _Float16* __restrict__ d1,
                     const _Float16* __restrict__ s1,
                     const float* __restrict__ W /*[27,96,2]*/,
                     const int* __restrict__ map, int N,
                     float* __restrict__ out)
{
    const int tid  = threadIdx.x;
    const int lane = tid & 63;
    const int l32  = tid & 31;
    const int i    = blockIdx.x * 8 + (tid >> 5);

    int mk = (l32 < 27 && i < N) ? map[(size_t)l32 * N + i] : -1;
    const unsigned long long bal = __ballot(mk >= 0);
    unsigned int act = (unsigned int)((bal | (bal >> 32)) & 0x7FFFFFFu);

    float x0 = 0.f, x1 = 0.f, x2 = 0.f;
    if (i < N) {
        x0 = (float)d1[(size_t)i * 64 + l32];
        x1 = (float)d1[(size_t)i * 64 + 32 + l32];
        x2 = (float)s1[(size_t)i * 32 + l32];
    }

    while (act) {
        const int k = (int)__builtin_ctz(act);
        act &= act - 1;
        const int j = __shfl(mk, (lane & 32) + k);   // dest row (or -1)
        const float* w = W + (size_t)(26 - k) * 96 * 2;
        float a0 = x0 * w[l32 * 2 + 0];
        float a1 = x0 * w[l32 * 2 + 1];
        a0 = fmaf(x1, w[(l32 + 32) * 2 + 0], a0);
        a1 = fmaf(x1, w[(l32 + 32) * 2 + 1], a1);
        a0 = fmaf(x2, w[(l32 + 64) * 2 + 0], a0);
        a1 = fmaf(x2, w[(l32 + 64) * 2 + 1], a1);
        // paired reduce: even lanes carry a0-chain, odd lanes a1-chain
        float s = (l32 & 1) ? a1 : a0;
        const float o = (l32 & 1) ? a0 : a1;
        s += __shfl_xor(o, 1, 32);
        s += __shfl_xor(s, 2, 32);
        s += __shfl_xor(s, 4, 32);
        s += __shfl_xor(s, 8, 32);
        s += __shfl_xor(s, 16, 32);
        if (l32 < 2 && j >= 0)
            atomicAdd(&out[(size_t)j * 2 + l32], s);
    }
}

// ---------------------------------------------------------------------------
// BN pass 1 on half tensors
// ---------------------------------------------------------------------------
template<int C>
__global__ __launch_bounds__(256)
void bn_reduce_h(const _Float16* __restrict__ x, int N,
                 float* __restrict__ sums)
{
    constexpr int RG = 256 / C;
    const int tid = threadIdx.x;
    const int c   = tid % C;
    const int rg  = tid / C;
    float s = 0.f, s2 = 0.f;
    for (int j = blockIdx.x * RG + rg; j < N; j += gridDim.x * RG) {
        const float v = (float)x[(size_t)j * C + c];
        s += v;
        s2 += v * v;
    }
    __shared__ float sh[2 * 256];
    sh[tid] = s;
    sh[256 + tid] = s2;
    __syncthreads();
    for (int stride = 128; stride >= C; stride >>= 1) {
        if (tid < stride) {
            sh[tid] += sh[tid + stride];
            sh[256 + tid] += sh[256 + tid + stride];
        }
        __syncthreads();
    }
    if (tid < C) {
        atomicAdd(&sums[c], sh[tid]);
        atomicAdd(&sums[C + c], sh[256 + tid]);
    }
}

// ---------------------------------------------------------------------------
// BN pass 2 on half tensors
// ---------------------------------------------------------------------------
template<int C>
__global__ __launch_bounds__(256)
void bn_apply_h(_Float16* __restrict__ x, int N,
                const float* __restrict__ sums,
                const float* __restrict__ g, const float* __restrict__ b)
{
    const int tid = blockIdx.x * blockDim.x + threadIdx.x;
    const int c = tid % C;
    const float invN = 1.0f / (float)N;
    const float mean = sums[c] * invN;
    float var = sums[C + c] * invN - mean * mean;
    var = fmaxf(var, 0.f);
    const float sc = g[c] * rsqrtf(var + BN_EPS);
    const float sh = b[c] - mean * sc;
    const int rows_stride = (gridDim.x * blockDim.x) / C;
    for (int j = tid / C; j < N; j += rows_stride) {
        const size_t i = (size_t)j * C + c;
        const float v = fmaf((float)x[i], sc, sh);
        x[i] = (_Float16)(v > 0.f ? v : 0.f);
    }
}

// ---------------------------------------------------------------------------
extern "C" void kernel_launch(void* const* d_in, const int* in_sizes, int n_in,
                              void* d_out, int out_size, void* d_ws, size_t ws_size,
                              hipStream_t stream)
{
    const float* feats = (const float*)d_in[0];
    const float* W0  = (const float*)d_in[1];
    const float* g0  = (const float*)d_in[2];
    const float* b0  = (const float*)d_in[3];
    const float* W1  = (const float*)d_in[4];
    const float* g1  = (const float*)d_in[5];
    const float* b1  = (const float*)d_in[6];
    const float* W2  = (const float*)d_in[7];
    const float* g2  = (const float*)d_in[8];
    const float* b2  = (const float*)d_in[9];
    const float* W2t = (const float*)d_in[10];
    const float* g2t = (const float*)d_in[11];
    const float* b2t = (const float*)d_in[12];
    const float* W1t = (const float*)d_in[13];
    const float* g1t = (const float*)d_in[14];
    const float* b1t = (const float*)d_in[15];
    const float* W0t = (const float*)d_in[16];
    const int* map0  = (const int*)d_in[17];
    const int* map1  = (const int*)d_in[18];
    const int* map2  = (const int*)d_in[19];
    const int* map2t = (const int*)d_in[20];
    const int* map1t = (const int*)d_in[21];
    const int* map0t = (const int*)d_in[22];

    const int N0 = in_sizes[0] / 16;
    const int N1 = in_sizes[18] / 27;
    const int N2 = in_sizes[19] / 27;

    const int Npad0 = (N0 + 15) & ~15;
    const int Npad1 = (N1 + 15) & ~15;

    float* ws = (float*)d_ws;
    float* sums  = ws;          // 704 floats of BN accumulators
    float* sums0 = sums;        // 2*32
    float* sums1 = sums + 64;   // 2*64
    float* sums2 = sums + 192;  // 2*128
    float* sums3 = sums + 448;  // 2*64
    float* sums4 = sums + 576;  // 2*64
    float* zrow  = sums + 704;  // 128 zeroed floats (fp32 & f16 zero rows)
    int*   gcnt  = (int*)(zrow + 128);  // 64 ints: 2x gcursor[9] regions
    _Float16* Wm0h = (_Float16*)(gcnt + 64);    // 27*2*32*8 f16 (paired MFMA)
    _Float16* Wh1  = Wm0h + 27 * 2 * 32 * 8;    // 27*32*64  (r1 layout)
    _Float16* Wh2  = Wh1 + 27 * 32 * 64;        // 27*64*128  (MFMA layout)
    _Float16* Wh2t = Wh2 + 27 * 64 * 128;       // 27*128*64  (MFMA layout)
    _Float16* Wh1t = Wh2t + 27 * 128 * 64;      // 27*128*64  (MFMA layout)
    _Float16* y0 = Wh1t + 27 * 128 * 64;        // [N0,32]  s1
    _Float16* y1 = y0 + (size_t)N0 * 32;        // [N1,64]  s2
    _Float16* y2 = y1 + (size_t)N1 * 64;        // [N2,128] s4
    _Float16* y3 = y2 + (size_t)N2 * 128;       // [N1,64]  d2
    _Float16* y4 = y3 + (size_t)N1 * 64;        // [N0,64]  d1
    int* mapT = (int*)(y4 + (size_t)N0 * 64);   // [Nmax,32] transposed map
    int* orderA = mapT + (size_t)N0 * 32;       // [9*Npad1] block2_tr groups
    int* orderB = orderA + (size_t)9 * Npad1;   // [9*Npad0] block1_tr groups
    const _Float16* zrh = (const _Float16*)zrow;

    (void)hipMemsetAsync(sums, 0, (704 + 128 + 64) * sizeof(float), stream);
    (void)hipMemsetAsync(orderA, 0xFF,
                         (size_t)9 * (Npad1 + Npad0) * sizeof(int), stream);
    (void)hipMemsetAsync(d_out, 0, out_size, stream);   // scatter conv0t target

    // weight transposes (tiny)
    wtrans_mf0<<<(27 * 2 * 32 + 255) / 256, 256, 0, stream>>>(W0, Wm0h);
    wtrans_h<32, 64><<<(27 * 4 * 64 + 255) / 256, 256, 0, stream>>>(W1, Wh1);
    wtrans_mf<64, 128><<<(27 * 2 * 8 * 64 + 255) / 256, 256, 0, stream>>>(W2, Wh2);
    wtrans_mf<128, 64><<<(27 * 4 * 4 * 64 + 255) / 256, 256, 0, stream>>>(W2t, Wh2t);
    wtrans_mf<128, 64><<<(27 * 4 * 4 * 64 + 255) / 256, 256, 0, stream>>>(W1t, Wh1t);

    // block0: feats[N0,16] fp32 -> y0[N0,32] half. MFMA k-paired hi/lo.
    sconv_mf0<<<(N0 + 63) / 64, 256, 0, stream>>>(
        feats, Wm0h, map0, N0, y0, zrow);
    bn_reduce_h<32><<<256, 256, 0, stream>>>(y0, N0, sums0);
    bn_apply_h<32><<<512, 256, 0, stream>>>(y0, N0, sums0, g0, b0);

    // block1 (SPARSE map, ~1.3 k/row): one wave per row (scalar dot2 path)
    map_transpose<<<(N1 + 255) / 256, 256, 0, stream>>>(map1, N1, mapT);
    sconv_r1<32, 32, 64><<<(N1 + 3) / 4, 256, 0, stream>>>(
        y0, nullptr, Wh1, mapT, N1, y1);
    bn_reduce_h<64><<<256, 256, 0, stream>>>(y1, N1, sums1);
    bn_apply_h<64><<<512, 256, 0, stream>>>(y1, N1, sums1, g1, b1);

    // block2: MFMA ungrouped, 32 rows/wave
    sconv_mf<64, 64, 128><<<(N2 + 127) / 128, 256, 0, stream>>>(
        y1, nullptr, Wh2, map2, N2, y2, zrh);
    bn_reduce_h<128><<<256, 256, 0, stream>>>(y2, N2, sums2);
    bn_apply_h<128><<<512, 256, 0, stream>>>(y2, N2, sums2, g2, b2);

    // block2_tr: parity-grouped MFMA, 32 rows/wave
    map_transpose_grp<<<(N1 + 255) / 256, 256, 0, stream>>>(
        map2t, N1, Npad1, mapT, gcnt, orderA);
    sconv_mf_g<128, 128, 64><<<(9 * Npad1 + 127) / 128, 256, 0, stream>>>(
        y2, nullptr, Wh2t, mapT, orderA, 9 * Npad1, N1, y3, zrh);
    bn_reduce_h<64><<<256, 256, 0, stream>>>(y3, N1, sums3);
    bn_apply_h<64><<<512, 256, 0, stream>>>(y3, N1, sums3, g2t, b2t);

    // block1_tr: parity-grouped MFMA, 32 rows/wave, concat (y3[64] ++ y1[64])
    map_transpose_grp<<<(N0 + 255) / 256, 256, 0, stream>>>(
        map1t, N0, Npad0, mapT, gcnt + 32, orderB);
    sconv_mf_g<128, 64, 64><<<(9 * Npad0 + 127) / 128, 256, 0, stream>>>(
        y3, y1, Wh1t, mapT, orderB, 9 * Npad0, N0, y4, zrh);
    bn_reduce_h<64><<<256, 256, 0, stream>>>(y4, N0, sums4);
    bn_apply_h<64><<<512, 256, 0, stream>>>(y4, N0, sums4, g1t, b1t);

    // block0_tr: scatter-atomic conv (self-inverse map, streamed input)
    sconv0t_scatter<<<(N0 + 7) / 8, 256, 0, stream>>>(
        y4, y0, W0t, map0t, N0, (float*)d_out);
}

// Round 10
// 692.790 us; speedup vs baseline: 1.2270x; 1.2270x over previous
//
#include <hip/hip_runtime.h>
#include <cstddef>
#include <cstdint>

#define BN_EPS 1e-5f

typedef float f4 __attribute__((ext_vector_type(4)));
typedef float f32x4 __attribute__((ext_vector_type(4)));
typedef _Float16 h2 __attribute__((ext_vector_type(2)));
typedef _Float16 h8 __attribute__((ext_vector_type(8)));

#if defined(__has_builtin)
#if __has_builtin(__builtin_amdgcn_fdot2)
#define DOT2(a, b, c) __builtin_amdgcn_fdot2((a), (b), (c), false)
#endif
#endif
#ifndef DOT2
#define DOT2(a, b, c) fmaf((float)(a)[1], (float)(b)[1], fmaf((float)(a)[0], (float)(b)[0], (c)))
#endif

// ---------------------------------------------------------------------------
// f16 weight transpose (sconv_r1): W[27][CIN][COUT] -> Wh[k][ci/8][co][8]
// ---------------------------------------------------------------------------
template<int CIN, int COUT>
__global__ __launch_bounds__(256)
void wtrans_h(const float* __restrict__ W, _Float16* __restrict__ Wh)
{
    const int t = blockIdx.x * 256 + threadIdx.x;
    constexpr int TOTAL = 27 * (CIN / 8) * COUT;
    if (t >= TOTAL) return;
    const int co = t % COUT;
    const int rest = t / COUT;
    const int t8 = rest % (CIN / 8);
    const int k  = rest / (CIN / 8);
    h8 v;
    #pragma unroll
    for (int u = 0; u < 8; ++u)
        v[u] = (_Float16)W[((size_t)k * CIN + t8 * 8 + u) * COUT + co];
    *(h8*)(Wh + (size_t)t * 8) = v;
}

// ---------------------------------------------------------------------------
// MFMA weight transform: W[27][CIN][COUT] fp32 -> B-fragment layout f16:
// Wm[((k*NT + t)*NC + ct)*64 + lane][8], h8 holds B[kk][co] with
// kk = t*32 + (lane>>4)*8 + u, co = ct*16 + (lane&15).
// ---------------------------------------------------------------------------
template<int CIN, int COUT>
__global__ __launch_bounds__(256)
void wtrans_mf(const float* __restrict__ W, _Float16* __restrict__ Wm)
{
    constexpr int NT = CIN / 32;
    constexpr int NC = COUT / 16;
    const int t = blockIdx.x * 256 + threadIdx.x;
    constexpr int TOTAL = 27 * NT * NC * 64;
    if (t >= TOTAL) return;
    const int lane = t & 63;
    int rest = t >> 6;
    const int ct = rest % NC; rest /= NC;
    const int tt = rest % NT;
    const int k  = rest / NT;
    const int cin0 = tt * 32 + (lane >> 4) * 8;
    const int co   = ct * 16 + (lane & 15);
    h8 v;
    #pragma unroll
    for (int u = 0; u < 8; ++u)
        v[u] = (_Float16)W[((size_t)k * CIN + cin0 + u) * COUT + co];
    *(h8*)(Wm + (size_t)t * 8) = v;
}

// ---------------------------------------------------------------------------
// conv0 MFMA weight transform (CIN=16, COUT=32, k-PAIRED):
// Wm0[((k*2 + s)*32 + co)*8 + u] = f16(W0[k][s*8+u][co]).
// ---------------------------------------------------------------------------
__global__ __launch_bounds__(256)
void wtrans_mf0(const float* __restrict__ W, _Float16* __restrict__ Wm0)
{
    const int t = blockIdx.x * 256 + threadIdx.x;
    constexpr int TOTAL = 27 * 2 * 32;
    if (t >= TOTAL) return;
    const int co = t % 32;
    const int s  = (t / 32) % 2;
    const int k  = t / 64;
    h8 v;
    #pragma unroll
    for (int u = 0; u < 8; ++u)
        v[u] = (_Float16)W[((size_t)k * 16 + s * 8 + u) * 32 + co];
    *(h8*)(Wm0 + (size_t)t * 8) = v;
}

// ---------------------------------------------------------------------------
// Map transpose: map[27][Nout] -> mapT[Nout][32] (k-major per row, -1 pad).
// ---------------------------------------------------------------------------
__global__ __launch_bounds__(256)
void map_transpose(const int* __restrict__ map, int Nout,
                   int* __restrict__ mapT)
{
    __shared__ int s[256][28];
    const int tid  = threadIdx.x;
    const int base = blockIdx.x * 256;
    const int j    = base + tid;
    for (int k = 0; k < 27; ++k)
        s[tid][k] = (j < Nout) ? map[(size_t)k * Nout + j] : -1;
    __syncthreads();
    for (int i = tid; i < 256 * 32; i += 256) {
        const int r = i >> 5, c = i & 31;
        if (base + r < Nout)
            mapT[(size_t)(base + r) * 32 + c] = (c < 27) ? s[r][c] : -1;
    }
}

// ---------------------------------------------------------------------------
// Map transpose + parity-class GROUPING, contention-free: LDS histogram ->
// 9 global atomics PER BLOCK -> LDS cursors. Class regions fixed at c*Npad
// in order[] (unfilled slots stay -1, pre-memset 0xFF). Perf heuristic only.
// ---------------------------------------------------------------------------
__global__ __launch_bounds__(256)
void map_transpose_grp(const int* __restrict__ map, int Nout, int Npad,
                       int* __restrict__ mapT, int* __restrict__ gcursor,
                       int* __restrict__ order)
{
    __shared__ int s[256][28];
    __shared__ int hist[9], basec[9], cur[9];
    const int tid  = threadIdx.x;
    const int base = blockIdx.x * 256;
    const int j    = base + tid;
    if (tid < 9) { hist[tid] = 0; cur[tid] = 0; }
    for (int k = 0; k < 27; ++k)
        s[tid][k] = (j < Nout) ? map[(size_t)k * Nout + j] : -1;
    __syncthreads();
    for (int i = tid; i < 256 * 32; i += 256) {
        const int r = i >> 5, c = i & 31;
        if (base + r < Nout)
            mapT[(size_t)(base + r) * 32 + c] = (c < 27) ? s[r][c] : -1;
    }
    int c9 = 8;
    if (j < Nout) {
        #pragma unroll 1
        for (int k = 0; k < 27; ++k) {
            if (s[tid][k] >= 0) {
                const int dz = k % 3, dy = (k / 3) % 3, dx = k / 9;
                c9 = ((dx != 1) << 2) | ((dy != 1) << 1) | (int)(dz != 1);
                break;
            }
        }
        atomicAdd(&hist[c9], 1);
    }
    __syncthreads();
    if (tid < 9 && hist[tid] > 0)
        basec[tid] = atomicAdd(&gcursor[tid], hist[tid]);
    __syncthreads();
    if (j < Nout) {
        const int lpos = atomicAdd(&cur[c9], 1);
        order[(size_t)c9 * Npad + basec[c9] + lpos] = j;
    }
}

// ---------------------------------------------------------------------------
// R=1 f16 sparse conv (SPARSE maps): one wave = one row. (block1)
// ---------------------------------------------------------------------------
template<int CIN, int CINA, int COUT>
__global__ __launch_bounds__(256)
void sconv_r1(const _Float16* __restrict__ xA, const _Float16* __restrict__ xB,
              const _Float16* __restrict__ Wh, const int* __restrict__ mapT,
              int Nout, _Float16* __restrict__ out)
{
    constexpr int CINB = CIN - CINA;
    constexpr int CPL  = COUT / 64;
    constexpr int NT   = CIN / 8;
    const int lane = threadIdx.x & 63;
    const int j    = blockIdx.x * 4 + (threadIdx.x >> 6);

    int mk = -1;
    if (j < Nout && lane < 32) mk = mapT[(size_t)j * 32 + lane];
    unsigned long long act = __ballot(mk >= 0);   // bits 0..26 only

    float acc[CPL];
    #pragma unroll
    for (int c = 0; c < CPL; ++c) acc[c] = 0.f;

    while (act) {
        const int k = (int)__builtin_ctzll(act);
        act &= act - 1;
        const int m = __builtin_amdgcn_readlane(mk, k);   // uniform SGPR

        const _Float16* pA = xA + (size_t)m * CINA;
        const _Float16* pB = nullptr;
        if constexpr (CINB > 0) pB = xB + (size_t)m * CINB;

        const _Float16* Wk = Wh + (size_t)k * NT * COUT * 8;

        #pragma unroll
        for (int t = 0; t < NT; ++t) {
            const int ci = t * 8;
            h8 wv[CPL];
            #pragma unroll
            for (int c = 0; c < CPL; ++c)
                wv[c] = *(const h8*)(Wk + ((size_t)t * COUT + c * 64 + lane) * 8);
            const _Float16* p;
            if constexpr (CINB > 0)
                p = (ci < CINA) ? (pA + ci) : (pB + (ci - CINA));
            else
                p = pA + ci;
            const h8 xv = *(const h8*)p;
            const h2* xp = (const h2*)&xv;
            #pragma unroll
            for (int q = 0; q < 4; ++q) {
                #pragma unroll
                for (int c = 0; c < CPL; ++c) {
                    const h2* wp = (const h2*)&wv[c];
                    acc[c] = DOT2(xp[q], wp[q], acc[c]);
                }
            }
        }
    }

    if (j < Nout) {
        #pragma unroll
        for (int c = 0; c < CPL; ++c)
            out[(size_t)j * COUT + c * 64 + lane] = (_Float16)acc[c];
    }
}

// ---------------------------------------------------------------------------
// conv0 MFMA (CIN=16 fp32 in, COUT=32, k-PAIRED, compensated hi/lo).
// ---------------------------------------------------------------------------
__global__ __launch_bounds__(256)
void sconv_mf0(const float* __restrict__ x, const _Float16* __restrict__ Wm0,
               const int* __restrict__ map, int Nout,
               _Float16* __restrict__ out, const float* __restrict__ zrow)
{
    const int lane = threadIdx.x & 63;
    const int wave = threadIdx.x >> 6;
    const int row0 = (blockIdx.x * 4 + wave) * 16;

    __shared__ int smap[4][16][28];

    int mk[16];
    bool anyv = false;
    #pragma unroll
    for (int r = 0; r < 16; ++r) {
        const int j = row0 + r;
        mk[r] = (lane < 27 && j < Nout) ? map[(size_t)lane * Nout + j] : -1;
        anyv |= (mk[r] >= 0);
    }
    unsigned long long act = __ballot(anyv);

    if (lane < 27) {
        #pragma unroll
        for (int r = 0; r < 16; ++r)
            smap[wave][r][lane] = mk[r];
    }

    f32x4 accH[2], accL[2];
    #pragma unroll
    for (int c = 0; c < 2; ++c) {
        accH[c] = (f32x4){0.f, 0.f, 0.f, 0.f};
        accL[c] = (f32x4){0.f, 0.f, 0.f, 0.f};
    }

    const int rrow = lane & 15;   // A row / D col
    const int kseg = lane >> 4;
    const int half = kseg & 1;    // cin half: 0 -> 0..7, 1 -> 8..15
    const bool useK1 = (kseg < 2);

    while (act) {
        const int k1 = (int)__builtin_ctzll(act);
        act &= act - 1;
        int k2 = -1;
        if (act) {
            k2 = (int)__builtin_ctzll(act);
            act &= act - 1;
        }
        const int ks = useK1 ? k1 : k2;
        int m = -1;
        if (ks >= 0) m = smap[wave][rrow][ks];

        const float* px = (m >= 0) ? (x + (size_t)m * 16 + half * 8)
                                   : (zrow + half * 8);
        const f4 x0 = *(const f4*)px;
        const f4 x1 = *(const f4*)(px + 4);
        h8 aH, aL;
        #pragma unroll
        for (int u = 0; u < 4; ++u) {
            const float v0 = x0[u], v1 = x1[u];
            const _Float16 h0 = (_Float16)v0;
            const _Float16 h1 = (_Float16)v1;
            aH[u]     = h0;
            aH[u + 4] = h1;
            aL[u]     = (_Float16)((v0 - (float)h0) * 2048.f);
            aL[u + 4] = (_Float16)((v1 - (float)h1) * 2048.f);
        }

        const int ksafe = (ks >= 0) ? ks : 0;   // a==0 makes b irrelevant
        const _Float16* wb = Wm0 + ((size_t)(ksafe * 2 + half) * 32) * 8;
        #pragma unroll
        for (int c = 0; c < 2; ++c) {
            const h8 b = *(const h8*)(wb + (size_t)(c * 16 + rrow) * 8);
            accH[c] = __builtin_amdgcn_mfma_f32_16x16x32_f16(aH, b, accH[c], 0, 0, 0);
            accL[c] = __builtin_amdgcn_mfma_f32_16x16x32_f16(aL, b, accL[c], 0, 0, 0);
        }
    }

    #pragma unroll
    for (int c = 0; c < 2; ++c) {
        #pragma unroll
        for (int r = 0; r < 4; ++r) {
            const int j = row0 + kseg * 4 + r;
            if (j < Nout)
                out[(size_t)j * 32 + c * 16 + rrow] =
                    (_Float16)(accH[c][r] + accL[c][r] * (1.f / 2048.f));
        }
    }
}

// ---------------------------------------------------------------------------
// MFMA sparse conv (UNGROUPED, raw map): one wave = 32 rows = TWO 16-row
// MFMA tiles sharing one k-union and the SAME B fragments. (block2)
// ---------------------------------------------------------------------------
template<int CIN, int CINA, int COUT>
__global__ __launch_bounds__(256)
void sconv_mf(const _Float16* __restrict__ xA, const _Float16* __restrict__ xB,
              const _Float16* __restrict__ Wm, const int* __restrict__ map,
              int Nout, _Float16* __restrict__ out,
              const _Float16* __restrict__ zrh)
{
    constexpr int CINB = CIN - CINA;
    constexpr int NT = CIN / 32;
    constexpr int NC = COUT / 16;
    static_assert(CINA % 32 == 0, "CINA must be a multiple of 32");
    const int lane = threadIdx.x & 63;
    const int wave = threadIdx.x >> 6;
    const int row0 = (blockIdx.x * 4 + wave) * 32;

    __shared__ int smap[4][32][28];

    bool anyv = false;
    #pragma unroll
    for (int r = 0; r < 32; ++r) {
        const int j = row0 + r;
        const int v = (lane < 27 && j < Nout) ? map[(size_t)lane * Nout + j] : -1;
        if (lane < 27) smap[wave][r][lane] = v;
        anyv |= (v >= 0);
    }
    unsigned long long act = __ballot(anyv) & 0x7FFFFFFull;

    f32x4 acc[2][NC];
    #pragma unroll
    for (int tt = 0; tt < 2; ++tt)
        #pragma unroll
        for (int c = 0; c < NC; ++c) acc[tt][c] = (f32x4){0.f, 0.f, 0.f, 0.f};

    const int rrow = lane & 15;
    const int kseg = lane >> 4;

    auto loada = [&](int k, h8 a[2][NT]) {
        #pragma unroll
        for (int tt = 0; tt < 2; ++tt) {
            const int m = smap[wave][tt * 16 + rrow][k];
            #pragma unroll
            for (int t = 0; t < NT; ++t) {
                const int cin0 = t * 32 + kseg * 8;
                const _Float16* pa;
                if (m >= 0) {
                    if (CINB > 0 && t * 32 >= CINA)
                        pa = xB + (size_t)m * CINB + (cin0 - CINA);
                    else
                        pa = xA + (size_t)m * CINA + cin0;
                } else {
                    pa = zrh;
                }
                a[tt][t] = *(const h8*)pa;
            }
        }
    };
    auto compute = [&](int k, h8 a[2][NT]) {
        const _Float16* Wk = Wm + ((size_t)k * NT * NC * 64 + lane) * 8;
        #pragma unroll
        for (int t = 0; t < NT; ++t) {
            #pragma unroll
            for (int c = 0; c < NC; ++c) {
                const h8 b = *(const h8*)(Wk + (size_t)(t * NC + c) * 64 * 8);
                acc[0][c] = __builtin_amdgcn_mfma_f32_16x16x32_f16(a[0][t], b, acc[0][c], 0, 0, 0);
                acc[1][c] = __builtin_amdgcn_mfma_f32_16x16x32_f16(a[1][t], b, acc[1][c], 0, 0, 0);
            }
        }
    };

    h8 aC[2][NT], aN[2][NT];
    int kC = -1;
    if (act) {
        kC = (int)__builtin_ctzll(act);
        act &= act - 1;
        loada(kC, aC);
    }
    while (kC >= 0) {
        int kN = -1;
        if (act) {
            kN = (int)__builtin_ctzll(act);
            act &= act - 1;
            loada(kN, aN);
        }
        compute(kC, aC);
        #pragma unroll
        for (int tt = 0; tt < 2; ++tt)
            #pragma unroll
            for (int t = 0; t < NT; ++t) aC[tt][t] = aN[tt][t];
        kC = kN;
    }

    #pragma unroll
    for (int tt = 0; tt < 2; ++tt) {
        #pragma unroll
        for (int c = 0; c < NC; ++c) {
            #pragma unroll
            for (int r = 0; r < 4; ++r) {
                const int j = row0 + tt * 16 + kseg * 4 + r;
                if (j < Nout)
                    out[(size_t)j * COUT + c * 16 + rrow] = (_Float16)acc[tt][c][r];
            }
        }
    }
}

// ---------------------------------------------------------------------------
// MFMA sparse conv (GROUPED): 32 order slots/wave, two 16-row MFMA tiles
// sharing the class k-union and B fragments. Dead waves exit early.
// ---------------------------------------------------------------------------
template<int CIN, int CINA, int COUT>
__global__ __launch_bounds__(256)
void sconv_mf_g(const _Float16* __restrict__ xA, const _Float16* __restrict__ xB,
                const _Float16* __restrict__ Wm, const int* __restrict__ mapT,
                const int* __restrict__ order, int NTOT, int Nout,
                _Float16* __restrict__ out, const _Float16* __restrict__ zrh)
{
    constexpr int CINB = CIN - CINA;
    constexpr int NT = CIN / 32;
    constexpr int NC = COUT / 16;
    static_assert(CINA % 32 == 0, "CINA must be a multiple of 32");
    const int lane = threadIdx.x & 63;
    const int wave = threadIdx.x >> 6;
    const int wrow0 = (blockIdx.x * 4 + wave) * 32;

    __shared__ int sjr[4][32];
    __shared__ int smap[4][32][28];

    int jreg = -1;
    if (lane < 32) {
        const int idx = wrow0 + lane;
        if (idx < NTOT) jreg = order[idx];
    }
    if (!__ballot(jreg >= 0)) return;     // dead wave: region tail padding
    if (lane < 32) sjr[wave][lane] = jreg;

    bool anyv = false;
    #pragma unroll
    for (int r = 0; r < 32; ++r) {
        const int jr = sjr[wave][r];      // wave-local LDS RAW (lgkmcnt)
        int v = -1;
        if (jr >= 0 && lane < 27) v = mapT[(size_t)jr * 32 + lane];
        if (lane < 27) smap[wave][r][lane] = v;
        anyv |= (v >= 0);
    }
    unsigned long long act = __ballot(anyv) & 0x7FFFFFFull;

    f32x4 acc[2][NC];
    #pragma unroll
    for (int tt = 0; tt < 2; ++tt)
        #pragma unroll
        for (int c = 0; c < NC; ++c) acc[tt][c] = (f32x4){0.f, 0.f, 0.f, 0.f};

    const int rrow = lane & 15;
    const int kseg = lane >> 4;

    auto loada = [&](int k, h8 a[2][NT]) {
        #pragma unroll
        for (int tt = 0; tt < 2; ++tt) {
            const int m = smap[wave][tt * 16 + rrow][k];
            #pragma unroll
            for (int t = 0; t < NT; ++t) {
                const int cin0 = t * 32 + kseg * 8;
                const _Float16* pa;
                if (m >= 0) {
                    if (CINB > 0 && t * 32 >= CINA)
                        pa = xB + (size_t)m * CINB + (cin0 - CINA);
                    else
                        pa = xA + (size_t)m * CINA + cin0;
                } else {
                    pa = zrh;
                }
                a[tt][t] = *(const h8*)pa;
            }
        }
    };
    auto compute = [&](int k, h8 a[2][NT]) {
        const _Float16* Wk = Wm + ((size_t)k * NT * NC * 64 + lane) * 8;
        #pragma unroll
        for (int t = 0; t < NT; ++t) {
            #pragma unroll
            for (int c = 0; c < NC; ++c) {
                const h8 b = *(const h8*)(Wk + (size_t)(t * NC + c) * 64 * 8);
                acc[0][c] = __builtin_amdgcn_mfma_f32_16x16x32_f16(a[0][t], b, acc[0][c], 0, 0, 0);
                acc[1][c] = __builtin_amdgcn_mfma_f32_16x16x32_f16(a[1][t], b, acc[1][c], 0, 0, 0);
            }
        }
    };

    h8 aC[2][NT], aN[2][NT];
    int kC = -1;
    if (act) {
        kC = (int)__builtin_ctzll(act);
        act &= act - 1;
        loada(kC, aC);
    }
    while (kC >= 0) {
        int kN = -1;
        if (act) {
            kN = (int)__builtin_ctzll(act);
            act &= act - 1;
            loada(kN, aN);
        }
        compute(kC, aC);
        #pragma unroll
        for (int tt = 0; tt < 2; ++tt)
            #pragma unroll
            for (int t = 0; t < NT; ++t) aC[tt][t] = aN[tt][t];
        kC = kN;
    }

    #pragma unroll
    for (int tt = 0; tt < 2; ++tt) {
        #pragma unroll
        for (int c = 0; c < NC; ++c) {
            #pragma unroll
            for (int r = 0; r < 4; ++r) {
                const int j = sjr[wave][tt * 16 + kseg * 4 + r];
                if (j >= 0)
                    out[(size_t)j * COUT + c * 16 + rrow] = (_Float16)acc[tt][c][r];
            }
        }
    }
}

// ---------------------------------------------------------------------------
// conv0t GATHER (reverted from round-9 scatter, which traded 92->61MB fetch
// for a serial shfl+atomic chain and regressed 75->84us): ctz-union loop.
// ---------------------------------------------------------------------------
__global__ __launch_bounds__(256)
void sconv0t(const _Float16* __restrict__ d1, const _Float16* __restrict__ s1,
             const float* __restrict__ W /*[27,96,2]*/,
             const int* __restrict__ map, int N, float* __restrict__ out,
             const _Float16* __restrict__ zrh)
{
    const int tid  = threadIdx.x;
    const int lane = tid & 63;
    const int l32  = tid & 31;
    const int j    = blockIdx.x * 8 + (tid >> 5);

    int mk = (l32 < 27 && j < N) ? map[(size_t)l32 * N + j] : -1;
    const unsigned long long bal = __ballot(mk >= 0);
    unsigned int act = (unsigned int)((bal | (bal >> 32)) & 0x7FFFFFFu);

    float a0 = 0.f, a1 = 0.f;
    while (act) {
        const int k = (int)__builtin_ctz(act);
        act &= act - 1;
        const int m = __shfl(mk, (lane & 32) + k);
        const _Float16* p1 = (m >= 0) ? (d1 + (size_t)m * 64) : zrh;
        const _Float16* p2 = (m >= 0) ? (s1 + (size_t)m * 32) : zrh;
        const float* w = W + (size_t)k * 96 * 2;
        const float x0 = (float)p1[l32];
        const float x1 = (float)p1[l32 + 32];
        const float x2 = (float)p2[l32];
        a0 = fmaf(x0, w[l32 * 2 + 0], a0);
        a1 = fmaf(x0, w[l32 * 2 + 1], a1);
        a0 = fmaf(x1, w[(l32 + 32) * 2 + 0], a0);
        a1 = fmaf(x1, w[(l32 + 32) * 2 + 1], a1);
        a0 = fmaf(x2, w[(l32 + 64) * 2 + 0], a0);
        a1 = fmaf(x2, w[(l32 + 64) * 2 + 1], a1);
    }
    #pragma unroll
    for (int off = 1; off < 32; off <<= 1) {
        a0 += __shfl_xor(a0, off, 32);
        a1 += __shfl_xor(a1, off, 32);
    }
    if (l32 == 0 && j < N) {
        out[(size_t)j * 2 + 0] = a0;
        out[(size_t)j * 2 + 1] = a1;
    }
}

// ---------------------------------------------------------------------------
// BN pass 1, VECTORIZED (round-10): one h8 (16B, 8 channels) per thread per
// step. Thread's channel-phase gid%(C/8) is loop-invariant (stride is a
// multiple of C/8), so 8-wide fp32 partials map to fixed channels. Wave
// butterfly with offsets >= CV preserves phase; LDS combine; one global
// atomic per channel per block. Scalar-f16 loads were the BN bottleneck
// (Common-mistake #2; ~2.4 vs ~5 TB/s effective).
// ---------------------------------------------------------------------------
template<int C>
__global__ __launch_bounds__(256)
void bn_reduce_v(const _Float16* __restrict__ x, int N,
                 float* __restrict__ sums)
{
    constexpr int CV = C / 8;   // h8 vectors per row (4, 8, or 16)
    const int tid  = threadIdx.x;
    const int lane = tid & 63;
    const int wave = tid >> 6;
    const size_t total  = (size_t)N * CV;
    const size_t stride = (size_t)gridDim.x * 256;   // multiple of CV
    const size_t gid    = (size_t)blockIdx.x * 256 + tid;

    float s[8], s2[8];
    #pragma unroll
    for (int u = 0; u < 8; ++u) { s[u] = 0.f; s2[u] = 0.f; }

    for (size_t v = gid; v < total; v += stride) {
        const h8 hv = *(const h8*)(x + v * 8);
        #pragma unroll
        for (int u = 0; u < 8; ++u) {
            const float f = (float)hv[u];
            s[u] += f;
            s2[u] += f * f;
        }
    }

    // butterfly over lanes with the same phase (offsets multiple of CV)
    #pragma unroll
    for (int off = CV; off < 64; off <<= 1) {
        #pragma unroll
        for (int u = 0; u < 8; ++u) {
            s[u]  += __shfl_xor(s[u], off);
            s2[u] += __shfl_xor(s2[u], off);
        }
    }

    __shared__ float shs[4][16][8];
    __shared__ float shq[4][16][8];
    if (lane < CV) {
        #pragma unroll
        for (int u = 0; u < 8; ++u) {
            shs[wave][lane][u] = s[u];
            shq[wave][lane][u] = s2[u];
        }
    }
    __syncthreads();
    if (tid < C) {
        const int ph = tid >> 3, u = tid & 7;
        float ts = 0.f, tq = 0.f;
        #pragma unroll
        for (int w = 0; w < 4; ++w) {
            ts += shs[w][ph][u];
            tq += shq[w][ph][u];
        }
        atomicAdd(&sums[tid], ts);
        atomicAdd(&sums[C + tid], tq);
    }
}

// ---------------------------------------------------------------------------
// BN pass 2, VECTORIZED: h8 load -> 8x fma/relu -> h8 store.
// ---------------------------------------------------------------------------
template<int C>
__global__ __launch_bounds__(256)
void bn_apply_v(_Float16* __restrict__ x, int N,
                const float* __restrict__ sums,
                const float* __restrict__ g, const float* __restrict__ b)
{
    constexpr int CV = C / 8;
    const size_t total  = (size_t)N * CV;
    const size_t stride = (size_t)gridDim.x * 256;   // multiple of CV
    const size_t gid    = (size_t)blockIdx.x * 256 + threadIdx.x;
    const int phase = (int)(gid % CV);

    const float invN = 1.0f / (float)N;
    float sc[8], sh[8];
    #pragma unroll
    for (int u = 0; u < 8; ++u) {
        const int c = phase * 8 + u;
        const float mean = sums[c] * invN;
        float var = sums[C + c] * invN - mean * mean;
        var = fmaxf(var, 0.f);
        sc[u] = g[c] * rsqrtf(var + BN_EPS);
        sh[u] = b[c] - mean * sc[u];
    }

    for (size_t v = gid; v < total; v += stride) {
        h8 hv = *(h8*)(x + v * 8);
        #pragma unroll
        for (int u = 0; u < 8; ++u) {
            const float f = fmaf((float)hv[u], sc[u], sh[u]);
            hv[u] = (_Float16)(f > 0.f ? f : 0.f);
        }
        *(h8*)(x + v * 8) = hv;
    }
}

// ---------------------------------------------------------------------------
extern "C" void kernel_launch(void* const* d_in, const int* in_sizes, int n_in,
                              void* d_out, int out_size, void* d_ws, size_t ws_size,
                              hipStream_t stream)
{
    const float* feats = (const float*)d_in[0];
    const float* W0  = (const float*)d_in[1];
    const float* g0  = (const float*)d_in[2];
    const float* b0  = (const float*)d_in[3];
    const float* W1  = (const float*)d_in[4];
    const float* g1  = (const float*)d_in[5];
    const float* b1  = (const float*)d_in[6];
    const float* W2  = (const float*)d_in[7];
    const float* g2  = (const float*)d_in[8];
    const float* b2  = (const float*)d_in[9];
    const float* W2t = (const float*)d_in[10];
    const float* g2t = (const float*)d_in[11];
    const float* b2t = (const float*)d_in[12];
    const float* W1t = (const float*)d_in[13];
    const float* g1t = (const float*)d_in[14];
    const float* b1t = (const float*)d_in[15];
    const float* W0t = (const float*)d_in[16];
    const int* map0  = (const int*)d_in[17];
    const int* map1  = (const int*)d_in[18];
    const int* map2  = (const int*)d_in[19];
    const int* map2t = (const int*)d_in[20];
    const int* map1t = (const int*)d_in[21];
    const int* map0t = (const int*)d_in[22];

    const int N0 = in_sizes[0] / 16;
    const int N1 = in_sizes[18] / 27;
    const int N2 = in_sizes[19] / 27;

    const int Npad0 = (N0 + 15) & ~15;
    const int Npad1 = (N1 + 15) & ~15;

    float* ws = (float*)d_ws;
    float* sums  = ws;          // 704 floats of BN accumulators
    float* sums0 = sums;        // 2*32
    float* sums1 = sums + 64;   // 2*64
    float* sums2 = sums + 192;  // 2*128
    float* sums3 = sums + 448;  // 2*64
    float* sums4 = sums + 576;  // 2*64
    float* zrow  = sums + 704;  // 128 zeroed floats (fp32 & f16 zero rows)
    int*   gcnt  = (int*)(zrow + 128);  // 64 ints: 2x gcursor[9] regions
    _Float16* Wm0h = (_Float16*)(gcnt + 64);    // 27*2*32*8 f16 (paired MFMA)
    _Float16* Wh1  = Wm0h + 27 * 2 * 32 * 8;    // 27*32*64  (r1 layout)
    _Float16* Wh2  = Wh1 + 27 * 32 * 64;        // 27*64*128  (MFMA layout)
    _Float16* Wh2t = Wh2 + 27 * 64 * 128;       // 27*128*64  (MFMA layout)
    _Float16* Wh1t = Wh2t + 27 * 128 * 64;      // 27*128*64  (MFMA layout)
    _Float16* y0 = Wh1t + 27 * 128 * 64;        // [N0,32]  s1
    _Float16* y1 = y0 + (size_t)N0 * 32;        // [N1,64]  s2
    _Float16* y2 = y1 + (size_t)N1 * 64;        // [N2,128] s4
    _Float16* y3 = y2 + (size_t)N2 * 128;       // [N1,64]  d2
    _Float16* y4 = y3 + (size_t)N1 * 64;        // [N0,64]  d1
    int* mapT = (int*)(y4 + (size_t)N0 * 64);   // [Nmax,32] transposed map
    int* orderA = mapT + (size_t)N0 * 32;       // [9*Npad1] block2_tr groups
    int* orderB = orderA + (size_t)9 * Npad1;   // [9*Npad0] block1_tr groups
    const _Float16* zrh = (const _Float16*)zrow;

    (void)hipMemsetAsync(sums, 0, (704 + 128 + 64) * sizeof(float), stream);
    (void)hipMemsetAsync(orderA, 0xFF,
                         (size_t)9 * (Npad1 + Npad0) * sizeof(int), stream);

    // weight transposes (tiny)
    wtrans_mf0<<<(27 * 2 * 32 + 255) / 256, 256, 0, stream>>>(W0, Wm0h);
    wtrans_h<32, 64><<<(27 * 4 * 64 + 255) / 256, 256, 0, stream>>>(W1, Wh1);
    wtrans_mf<64, 128><<<(27 * 2 * 8 * 64 + 255) / 256, 256, 0, stream>>>(W2, Wh2);
    wtrans_mf<128, 64><<<(27 * 4 * 4 * 64 + 255) / 256, 256, 0, stream>>>(W2t, Wh2t);
    wtrans_mf<128, 64><<<(27 * 4 * 4 * 64 + 255) / 256, 256, 0, stream>>>(W1t, Wh1t);

    // block0: feats[N0,16] fp32 -> y0[N0,32] half. MFMA k-paired hi/lo.
    sconv_mf0<<<(N0 + 63) / 64, 256, 0, stream>>>(
        feats, Wm0h, map0, N0, y0, zrow);
    bn_reduce_v<32><<<512, 256, 0, stream>>>(y0, N0, sums0);
    bn_apply_v<32><<<1024, 256, 0, stream>>>(y0, N0, sums0, g0, b0);

    // block1 (SPARSE map, ~1.3 k/row): one wave per row (scalar dot2 path)
    map_transpose<<<(N1 + 255) / 256, 256, 0, stream>>>(map1, N1, mapT);
    sconv_r1<32, 32, 64><<<(N1 + 3) / 4, 256, 0, stream>>>(
        y0, nullptr, Wh1, mapT, N1, y1);
    bn_reduce_v<64><<<512, 256, 0, stream>>>(y1, N1, sums1);
    bn_apply_v<64><<<1024, 256, 0, stream>>>(y1, N1, sums1, g1, b1);

    // block2: MFMA ungrouped, 32 rows/wave
    sconv_mf<64, 64, 128><<<(N2 + 127) / 128, 256, 0, stream>>>(
        y1, nullptr, Wh2, map2, N2, y2, zrh);
    bn_reduce_v<128><<<512, 256, 0, stream>>>(y2, N2, sums2);
    bn_apply_v<128><<<1024, 256, 0, stream>>>(y2, N2, sums2, g2, b2);

    // block2_tr: parity-grouped MFMA, 32 rows/wave
    map_transpose_grp<<<(N1 + 255) / 256, 256, 0, stream>>>(
        map2t, N1, Npad1, mapT, gcnt, orderA);
    sconv_mf_g<128, 128, 64><<<(9 * Npad1 + 127) / 128, 256, 0, stream>>>(
        y2, nullptr, Wh2t, mapT, orderA, 9 * Npad1, N1, y3, zrh);
    bn_reduce_v<64><<<512, 256, 0, stream>>>(y3, N1, sums3);
    bn_apply_v<64><<<1024, 256, 0, stream>>>(y3, N1, sums3, g2t, b2t);

    // block1_tr: parity-grouped MFMA, 32 rows/wave, concat (y3[64] ++ y1[64])
    map_transpose_grp<<<(N0 + 255) / 256, 256, 0, stream>>>(
        map1t, N0, Npad0, mapT, gcnt + 32, orderB);
    sconv_mf_g<128, 64, 64><<<(9 * Npad0 + 127) / 128, 256, 0, stream>>>(
        y3, y1, Wh1t, mapT, orderB, 9 * Npad0, N0, y4, zrh);
    bn_reduce_v<64><<<512, 256, 0, stream>>>(y4, N0, sums4);
    bn_apply_v<64><<<1024, 256, 0, stream>>>(y4, N0, sums4, g1t, b1t);

    // block0_tr: gather conv -> out[N0,2] fp32
    sconv0t<<<(N0 + 7) / 8, 256, 0, stream>>>(y4, y0, W0t, map0t, N0,
                                              (float*)d_out, zrh);
}

// Round 11
// 662.903 us; speedup vs baseline: 1.2823x; 1.0451x over previous
//
#include <hip/hip_runtime.h>
#include <cstddef>
#include <cstdint>

#define BN_EPS 1e-5f

typedef float f2 __attribute__((ext_vector_type(2)));
typedef float f4 __attribute__((ext_vector_type(4)));
typedef float f32x4 __attribute__((ext_vector_type(4)));
typedef _Float16 h2 __attribute__((ext_vector_type(2)));
typedef _Float16 h8 __attribute__((ext_vector_type(8)));

// ---------------------------------------------------------------------------
// MFMA weight transform: W[27][CIN][COUT] fp32 -> B-fragment layout f16:
// Wm[((k*NT + t)*NC + ct)*64 + lane][8], h8 holds B[kk][co] with
// kk = t*32 + (lane>>4)*8 + u, co = ct*16 + (lane&15).
// ---------------------------------------------------------------------------
template<int CIN, int COUT>
__global__ __launch_bounds__(256)
void wtrans_mf(const float* __restrict__ W, _Float16* __restrict__ Wm)
{
    constexpr int NT = CIN / 32;
    constexpr int NC = COUT / 16;
    const int t = blockIdx.x * 256 + threadIdx.x;
    constexpr int TOTAL = 27 * NT * NC * 64;
    if (t >= TOTAL) return;
    const int lane = t & 63;
    int rest = t >> 6;
    const int ct = rest % NC; rest /= NC;
    const int tt = rest % NT;
    const int k  = rest / NT;
    const int cin0 = tt * 32 + (lane >> 4) * 8;
    const int co   = ct * 16 + (lane & 15);
    h8 v;
    #pragma unroll
    for (int u = 0; u < 8; ++u)
        v[u] = (_Float16)W[((size_t)k * CIN + cin0 + u) * COUT + co];
    *(h8*)(Wm + (size_t)t * 8) = v;
}

// ---------------------------------------------------------------------------
// conv0 MFMA weight transform (CIN=16, COUT=32, k-PAIRED):
// Wm0[((k*2 + s)*32 + co)*8 + u] = f16(W0[k][s*8+u][co]).
// ---------------------------------------------------------------------------
__global__ __launch_bounds__(256)
void wtrans_mf0(const float* __restrict__ W, _Float16* __restrict__ Wm0)
{
    const int t = blockIdx.x * 256 + threadIdx.x;
    constexpr int TOTAL = 27 * 2 * 32;
    if (t >= TOTAL) return;
    const int co = t % 32;
    const int s  = (t / 32) % 2;
    const int k  = t / 64;
    h8 v;
    #pragma unroll
    for (int u = 0; u < 8; ++u)
        v[u] = (_Float16)W[((size_t)k * 16 + s * 8 + u) * 32 + co];
    *(h8*)(Wm0 + (size_t)t * 8) = v;
}

// ---------------------------------------------------------------------------
// Map transpose + parity-class GROUPING, contention-free: LDS histogram ->
// 9 global atomics PER BLOCK -> LDS cursors. Class regions fixed at c*Npad
// in order[] (unfilled slots stay -1, pre-memset 0xFF). Perf heuristic only.
// ---------------------------------------------------------------------------
__global__ __launch_bounds__(256)
void map_transpose_grp(const int* __restrict__ map, int Nout, int Npad,
                       int* __restrict__ mapT, int* __restrict__ gcursor,
                       int* __restrict__ order)
{
    __shared__ int s[256][28];
    __shared__ int hist[9], basec[9], cur[9];
    const int tid  = threadIdx.x;
    const int base = blockIdx.x * 256;
    const int j    = base + tid;
    if (tid < 9) { hist[tid] = 0; cur[tid] = 0; }
    for (int k = 0; k < 27; ++k)
        s[tid][k] = (j < Nout) ? map[(size_t)k * Nout + j] : -1;
    __syncthreads();
    for (int i = tid; i < 256 * 32; i += 256) {
        const int r = i >> 5, c = i & 31;
        if (base + r < Nout)
            mapT[(size_t)(base + r) * 32 + c] = (c < 27) ? s[r][c] : -1;
    }
    int c9 = 8;
    if (j < Nout) {
        #pragma unroll 1
        for (int k = 0; k < 27; ++k) {
            if (s[tid][k] >= 0) {
                const int dz = k % 3, dy = (k / 3) % 3, dx = k / 9;
                c9 = ((dx != 1) << 2) | ((dy != 1) << 1) | (int)(dz != 1);
                break;
            }
        }
        atomicAdd(&hist[c9], 1);
    }
    __syncthreads();
    if (tid < 9 && hist[tid] > 0)
        basec[tid] = atomicAdd(&gcursor[tid], hist[tid]);
    __syncthreads();
    if (j < Nout) {
        const int lpos = atomicAdd(&cur[c9], 1);
        order[(size_t)c9 * Npad + basec[c9] + lpos] = j;
    }
}

// ---------------------------------------------------------------------------
// conv0 MFMA (CIN=16 fp32 in, COUT=32, k-PAIRED, compensated hi/lo).
// ---------------------------------------------------------------------------
__global__ __launch_bounds__(256)
void sconv_mf0(const float* __restrict__ x, const _Float16* __restrict__ Wm0,
               const int* __restrict__ map, int Nout,
               _Float16* __restrict__ out, const float* __restrict__ zrow)
{
    const int lane = threadIdx.x & 63;
    const int wave = threadIdx.x >> 6;
    const int row0 = (blockIdx.x * 4 + wave) * 16;

    __shared__ int smap[4][16][28];

    int mk[16];
    bool anyv = false;
    #pragma unroll
    for (int r = 0; r < 16; ++r) {
        const int j = row0 + r;
        mk[r] = (lane < 27 && j < Nout) ? map[(size_t)lane * Nout + j] : -1;
        anyv |= (mk[r] >= 0);
    }
    unsigned long long act = __ballot(anyv);

    if (lane < 27) {
        #pragma unroll
        for (int r = 0; r < 16; ++r)
            smap[wave][r][lane] = mk[r];
    }

    f32x4 accH[2], accL[2];
    #pragma unroll
    for (int c = 0; c < 2; ++c) {
        accH[c] = (f32x4){0.f, 0.f, 0.f, 0.f};
        accL[c] = (f32x4){0.f, 0.f, 0.f, 0.f};
    }

    const int rrow = lane & 15;   // A row / D col
    const int kseg = lane >> 4;
    const int half = kseg & 1;    // cin half: 0 -> 0..7, 1 -> 8..15
    const bool useK1 = (kseg < 2);

    while (act) {
        const int k1 = (int)__builtin_ctzll(act);
        act &= act - 1;
        int k2 = -1;
        if (act) {
            k2 = (int)__builtin_ctzll(act);
            act &= act - 1;
        }
        const int ks = useK1 ? k1 : k2;
        int m = -1;
        if (ks >= 0) m = smap[wave][rrow][ks];

        const float* px = (m >= 0) ? (x + (size_t)m * 16 + half * 8)
                                   : (zrow + half * 8);
        const f4 x0 = *(const f4*)px;
        const f4 x1 = *(const f4*)(px + 4);
        h8 aH, aL;
        #pragma unroll
        for (int u = 0; u < 4; ++u) {
            const float v0 = x0[u], v1 = x1[u];
            const _Float16 h0 = (_Float16)v0;
            const _Float16 h1 = (_Float16)v1;
            aH[u]     = h0;
            aH[u + 4] = h1;
            aL[u]     = (_Float16)((v0 - (float)h0) * 2048.f);
            aL[u + 4] = (_Float16)((v1 - (float)h1) * 2048.f);
        }

        const int ksafe = (ks >= 0) ? ks : 0;   // a==0 makes b irrelevant
        const _Float16* wb = Wm0 + ((size_t)(ksafe * 2 + half) * 32) * 8;
        #pragma unroll
        for (int c = 0; c < 2; ++c) {
            const h8 b = *(const h8*)(wb + (size_t)(c * 16 + rrow) * 8);
            accH[c] = __builtin_amdgcn_mfma_f32_16x16x32_f16(aH, b, accH[c], 0, 0, 0);
            accL[c] = __builtin_amdgcn_mfma_f32_16x16x32_f16(aL, b, accL[c], 0, 0, 0);
        }
    }

    #pragma unroll
    for (int c = 0; c < 2; ++c) {
        #pragma unroll
        for (int r = 0; r < 4; ++r) {
            const int j = row0 + kseg * 4 + r;
            if (j < Nout)
                out[(size_t)j * 32 + c * 16 + rrow] =
                    (_Float16)(accH[c][r] + accL[c][r] * (1.f / 2048.f));
        }
    }
}

// ---------------------------------------------------------------------------
// MFMA sparse conv (UNGROUPED, raw map): one wave = 32 rows = TWO 16-row
// MFMA tiles sharing one k-union and the SAME B fragments.
// Used for block2 (CIN=64) and, from round 11, block1 (CIN=32, NT=1) --
// replacing the last dot2 kernel (sconv_r1 re-loaded the 4KB W k-slice per
// ROW per k: ~0.9GB L1 traffic; 32-row sharing cuts it ~4x + MFMA pipe).
// ---------------------------------------------------------------------------
template<int CIN, int CINA, int COUT>
__global__ __launch_bounds__(256)
void sconv_mf(const _Float16* __restrict__ xA, const _Float16* __restrict__ xB,
              const _Float16* __restrict__ Wm, const int* __restrict__ map,
              int Nout, _Float16* __restrict__ out,
              const _Float16* __restrict__ zrh)
{
    constexpr int CINB = CIN - CINA;
    constexpr int NT = CIN / 32;
    constexpr int NC = COUT / 16;
    static_assert(CINA % 32 == 0, "CINA must be a multiple of 32");
    const int lane = threadIdx.x & 63;
    const int wave = threadIdx.x >> 6;
    const int row0 = (blockIdx.x * 4 + wave) * 32;

    __shared__ int smap[4][32][28];

    bool anyv = false;
    #pragma unroll
    for (int r = 0; r < 32; ++r) {
        const int j = row0 + r;
        const int v = (lane < 27 && j < Nout) ? map[(size_t)lane * Nout + j] : -1;
        if (lane < 27) smap[wave][r][lane] = v;
        anyv |= (v >= 0);
    }
    unsigned long long act = __ballot(anyv) & 0x7FFFFFFull;

    f32x4 acc[2][NC];
    #pragma unroll
    for (int tt = 0; tt < 2; ++tt)
        #pragma unroll
        for (int c = 0; c < NC; ++c) acc[tt][c] = (f32x4){0.f, 0.f, 0.f, 0.f};

    const int rrow = lane & 15;
    const int kseg = lane >> 4;

    auto loada = [&](int k, h8 a[2][NT]) {
        #pragma unroll
        for (int tt = 0; tt < 2; ++tt) {
            const int m = smap[wave][tt * 16 + rrow][k];
            #pragma unroll
            for (int t = 0; t < NT; ++t) {
                const int cin0 = t * 32 + kseg * 8;
                const _Float16* pa;
                if (m >= 0) {
                    if (CINB > 0 && t * 32 >= CINA)
                        pa = xB + (size_t)m * CINB + (cin0 - CINA);
                    else
                        pa = xA + (size_t)m * CINA + cin0;
                } else {
                    pa = zrh;
                }
                a[tt][t] = *(const h8*)pa;
            }
        }
    };
    auto compute = [&](int k, h8 a[2][NT]) {
        const _Float16* Wk = Wm + ((size_t)k * NT * NC * 64 + lane) * 8;
        #pragma unroll
        for (int t = 0; t < NT; ++t) {
            #pragma unroll
            for (int c = 0; c < NC; ++c) {
                const h8 b = *(const h8*)(Wk + (size_t)(t * NC + c) * 64 * 8);
                acc[0][c] = __builtin_amdgcn_mfma_f32_16x16x32_f16(a[0][t], b, acc[0][c], 0, 0, 0);
                acc[1][c] = __builtin_amdgcn_mfma_f32_16x16x32_f16(a[1][t], b, acc[1][c], 0, 0, 0);
            }
        }
    };

    h8 aC[2][NT], aN[2][NT];
    int kC = -1;
    if (act) {
        kC = (int)__builtin_ctzll(act);
        act &= act - 1;
        loada(kC, aC);
    }
    while (kC >= 0) {
        int kN = -1;
        if (act) {
            kN = (int)__builtin_ctzll(act);
            act &= act - 1;
            loada(kN, aN);
        }
        compute(kC, aC);
        #pragma unroll
        for (int tt = 0; tt < 2; ++tt)
            #pragma unroll
            for (int t = 0; t < NT; ++t) aC[tt][t] = aN[tt][t];
        kC = kN;
    }

    #pragma unroll
    for (int tt = 0; tt < 2; ++tt) {
        #pragma unroll
        for (int c = 0; c < NC; ++c) {
            #pragma unroll
            for (int r = 0; r < 4; ++r) {
                const int j = row0 + tt * 16 + kseg * 4 + r;
                if (j < Nout)
                    out[(size_t)j * COUT + c * 16 + rrow] = (_Float16)acc[tt][c][r];
            }
        }
    }
}

// ---------------------------------------------------------------------------
// MFMA sparse conv (GROUPED): 32 order slots/wave, two 16-row MFMA tiles
// sharing the class k-union and B fragments. Dead waves exit early.
// ---------------------------------------------------------------------------
template<int CIN, int CINA, int COUT>
__global__ __launch_bounds__(256)
void sconv_mf_g(const _Float16* __restrict__ xA, const _Float16* __restrict__ xB,
                const _Float16* __restrict__ Wm, const int* __restrict__ mapT,
                const int* __restrict__ order, int NTOT, int Nout,
                _Float16* __restrict__ out, const _Float16* __restrict__ zrh)
{
    constexpr int CINB = CIN - CINA;
    constexpr int NT = CIN / 32;
    constexpr int NC = COUT / 16;
    static_assert(CINA % 32 == 0, "CINA must be a multiple of 32");
    const int lane = threadIdx.x & 63;
    const int wave = threadIdx.x >> 6;
    const int wrow0 = (blockIdx.x * 4 + wave) * 32;

    __shared__ int sjr[4][32];
    __shared__ int smap[4][32][28];

    int jreg = -1;
    if (lane < 32) {
        const int idx = wrow0 + lane;
        if (idx < NTOT) jreg = order[idx];
    }
    if (!__ballot(jreg >= 0)) return;     // dead wave: region tail padding
    if (lane < 32) sjr[wave][lane] = jreg;

    bool anyv = false;
    #pragma unroll
    for (int r = 0; r < 32; ++r) {
        const int jr = sjr[wave][r];      // wave-local LDS RAW (lgkmcnt)
        int v = -1;
        if (jr >= 0 && lane < 27) v = mapT[(size_t)jr * 32 + lane];
        if (lane < 27) smap[wave][r][lane] = v;
        anyv |= (v >= 0);
    }
    unsigned long long act = __ballot(anyv) & 0x7FFFFFFull;

    f32x4 acc[2][NC];
    #pragma unroll
    for (int tt = 0; tt < 2; ++tt)
        #pragma unroll
        for (int c = 0; c < NC; ++c) acc[tt][c] = (f32x4){0.f, 0.f, 0.f, 0.f};

    const int rrow = lane & 15;
    const int kseg = lane >> 4;

    auto loada = [&](int k, h8 a[2][NT]) {
        #pragma unroll
        for (int tt = 0; tt < 2; ++tt) {
            const int m = smap[wave][tt * 16 + rrow][k];
            #pragma unroll
            for (int t = 0; t < NT; ++t) {
                const int cin0 = t * 32 + kseg * 8;
                const _Float16* pa;
                if (m >= 0) {
                    if (CINB > 0 && t * 32 >= CINA)
                        pa = xB + (size_t)m * CINB + (cin0 - CINA);
                    else
                        pa = xA + (size_t)m * CINA + cin0;
                } else {
                    pa = zrh;
                }
                a[tt][t] = *(const h8*)pa;
            }
        }
    };
    auto compute = [&](int k, h8 a[2][NT]) {
        const _Float16* Wk = Wm + ((size_t)k * NT * NC * 64 + lane) * 8;
        #pragma unroll
        for (int t = 0; t < NT; ++t) {
            #pragma unroll
            for (int c = 0; c < NC; ++c) {
                const h8 b = *(const h8*)(Wk + (size_t)(t * NC + c) * 64 * 8);
                acc[0][c] = __builtin_amdgcn_mfma_f32_16x16x32_f16(a[0][t], b, acc[0][c], 0, 0, 0);
                acc[1][c] = __builtin_amdgcn_mfma_f32_16x16x32_f16(a[1][t], b, acc[1][c], 0, 0, 0);
            }
        }
    };

    h8 aC[2][NT], aN[2][NT];
    int kC = -1;
    if (act) {
        kC = (int)__builtin_ctzll(act);
        act &= act - 1;
        loada(kC, aC);
    }
    while (kC >= 0) {
        int kN = -1;
        if (act) {
            kN = (int)__builtin_ctzll(act);
            act &= act - 1;
            loada(kN, aN);
        }
        compute(kC, aC);
        #pragma unroll
        for (int tt = 0; tt < 2; ++tt)
            #pragma unroll
            for (int t = 0; t < NT; ++t) aC[tt][t] = aN[tt][t];
        kC = kN;
    }

    #pragma unroll
    for (int tt = 0; tt < 2; ++tt) {
        #pragma unroll
        for (int c = 0; c < NC; ++c) {
            #pragma unroll
            for (int r = 0; r < 4; ++r) {
                const int j = sjr[wave][tt * 16 + kseg * 4 + r];
                if (j >= 0)
                    out[(size_t)j * COUT + c * 16 + rrow] = (_Float16)acc[tt][c][r];
            }
        }
    }
}

// ---------------------------------------------------------------------------
// conv0t GATHER, round-11: 2-k-per-iteration software pipeline (all 4 gather
// loads issue before any FMA -- doubles memory-level parallelism on the
// latency-bound shfl->load->fma chain) + vectorized loads: lane covers d1
// channels {2*l32, 2*l32+1} via one h2 (weights fold into one aligned f4)
// and s1 channel l32 (one f2 weight). Inactive k2 gathers from zrh -> +0.
// ---------------------------------------------------------------------------
__global__ __launch_bounds__(256)
void sconv0t(const _Float16* __restrict__ d1, const _Float16* __restrict__ s1,
             const float* __restrict__ W /*[27,96,2]*/,
             const int* __restrict__ map, int N, float* __restrict__ out,
             const _Float16* __restrict__ zrh)
{
    const int tid  = threadIdx.x;
    const int lane = tid & 63;
    const int l32  = tid & 31;
    const int j    = blockIdx.x * 8 + (tid >> 5);

    int mk = (l32 < 27 && j < N) ? map[(size_t)l32 * N + j] : -1;
    const unsigned long long bal = __ballot(mk >= 0);
    unsigned int act = (unsigned int)((bal | (bal >> 32)) & 0x7FFFFFFu);

    float a0 = 0.f, a1 = 0.f;
    while (act) {
        const int k1 = (int)__builtin_ctz(act);
        act &= act - 1;
        int k2 = -1;
        if (act) { k2 = (int)__builtin_ctz(act); act &= act - 1; }
        const int k2s = (k2 >= 0) ? k2 : k1;

        const int m1 = __shfl(mk, (lane & 32) + k1);
        int m2 = __shfl(mk, (lane & 32) + k2s);
        if (k2 < 0) m2 = -1;

        // issue ALL gathers before any FMA
        const _Float16* p1a = (m1 >= 0) ? (d1 + (size_t)m1 * 64) : zrh;
        const _Float16* p1b = (m1 >= 0) ? (s1 + (size_t)m1 * 32) : zrh;
        const _Float16* p2a = (m2 >= 0) ? (d1 + (size_t)m2 * 64) : zrh;
        const _Float16* p2b = (m2 >= 0) ? (s1 + (size_t)m2 * 32) : zrh;
        const h2 xa1 = *(const h2*)(p1a + 2 * l32);
        const float xs1 = (float)p1b[l32];
        const h2 xa2 = *(const h2*)(p2a + 2 * l32);
        const float xs2 = (float)p2b[l32];

        const f4 wa1 = *(const f4*)(W + (size_t)k1 * 192 + 4 * l32);
        const f2 ws1 = *(const f2*)(W + (size_t)k1 * 192 + 128 + 2 * l32);
        const f4 wa2 = *(const f4*)(W + (size_t)k2s * 192 + 4 * l32);
        const f2 ws2 = *(const f2*)(W + (size_t)k2s * 192 + 128 + 2 * l32);

        a0 = fmaf((float)xa1[0], wa1[0], a0);
        a1 = fmaf((float)xa1[0], wa1[1], a1);
        a0 = fmaf((float)xa1[1], wa1[2], a0);
        a1 = fmaf((float)xa1[1], wa1[3], a1);
        a0 = fmaf(xs1, ws1[0], a0);
        a1 = fmaf(xs1, ws1[1], a1);

        a0 = fmaf((float)xa2[0], wa2[0], a0);
        a1 = fmaf((float)xa2[0], wa2[1], a1);
        a0 = fmaf((float)xa2[1], wa2[2], a0);
        a1 = fmaf((float)xa2[1], wa2[3], a1);
        a0 = fmaf(xs2, ws2[0], a0);
        a1 = fmaf(xs2, ws2[1], a1);
    }
    #pragma unroll
    for (int off = 1; off < 32; off <<= 1) {
        a0 += __shfl_xor(a0, off, 32);
        a1 += __shfl_xor(a1, off, 32);
    }
    if (l32 == 0 && j < N) {
        out[(size_t)j * 2 + 0] = a0;
        out[(size_t)j * 2 + 1] = a1;
    }
}

// ---------------------------------------------------------------------------
// BN pass 1, VECTORIZED: one h8 (8 channels) per thread per step; fp32
// 8-wide partials on fixed channels; phase-preserving butterfly; LDS; one
// atomic per channel per block.
// ---------------------------------------------------------------------------
template<int C>
__global__ __launch_bounds__(256)
void bn_reduce_v(const _Float16* __restrict__ x, int N,
                 float* __restrict__ sums)
{
    constexpr int CV = C / 8;   // h8 vectors per row (4, 8, or 16)
    const int tid  = threadIdx.x;
    const int lane = tid & 63;
    const int wave = tid >> 6;
    const size_t total  = (size_t)N * CV;
    const size_t stride = (size_t)gridDim.x * 256;   // multiple of CV
    const size_t gid    = (size_t)blockIdx.x * 256 + tid;

    float s[8], s2[8];
    #pragma unroll
    for (int u = 0; u < 8; ++u) { s[u] = 0.f; s2[u] = 0.f; }

    for (size_t v = gid; v < total; v += stride) {
        const h8 hv = *(const h8*)(x + v * 8);
        #pragma unroll
        for (int u = 0; u < 8; ++u) {
            const float f = (float)hv[u];
            s[u] += f;
            s2[u] += f * f;
        }
    }

    #pragma unroll
    for (int off = CV; off < 64; off <<= 1) {
        #pragma unroll
        for (int u = 0; u < 8; ++u) {
            s[u]  += __shfl_xor(s[u], off);
            s2[u] += __shfl_xor(s2[u], off);
        }
    }

    __shared__ float shs[4][16][8];
    __shared__ float shq[4][16][8];
    if (lane < CV) {
        #pragma unroll
        for (int u = 0; u < 8; ++u) {
            shs[wave][lane][u] = s[u];
            shq[wave][lane][u] = s2[u];
        }
    }
    __syncthreads();
    if (tid < C) {
        const int ph = tid >> 3, u = tid & 7;
        float ts = 0.f, tq = 0.f;
        #pragma unroll
        for (int w = 0; w < 4; ++w) {
            ts += shs[w][ph][u];
            tq += shq[w][ph][u];
        }
        atomicAdd(&sums[tid], ts);
        atomicAdd(&sums[C + tid], tq);
    }
}

// ---------------------------------------------------------------------------
// BN pass 2, VECTORIZED: h8 load -> 8x fma/relu -> h8 store.
// ---------------------------------------------------------------------------
template<int C>
__global__ __launch_bounds__(256)
void bn_apply_v(_Float16* __restrict__ x, int N,
                const float* __restrict__ sums,
                const float* __restrict__ g, const float* __restrict__ b)
{
    constexpr int CV = C / 8;
    const size_t total  = (size_t)N * CV;
    const size_t stride = (size_t)gridDim.x * 256;   // multiple of CV
    const size_t gid    = (size_t)blockIdx.x * 256 + threadIdx.x;
    const int phase = (int)(gid % CV);

    const float invN = 1.0f / (float)N;
    float sc[8], sh[8];
    #pragma unroll
    for (int u = 0; u < 8; ++u) {
        const int c = phase * 8 + u;
        const float mean = sums[c] * invN;
        float var = sums[C + c] * invN - mean * mean;
        var = fmaxf(var, 0.f);
        sc[u] = g[c] * rsqrtf(var + BN_EPS);
        sh[u] = b[c] - mean * sc[u];
    }

    for (size_t v = gid; v < total; v += stride) {
        h8 hv = *(h8*)(x + v * 8);
        #pragma unroll
        for (int u = 0; u < 8; ++u) {
            const float f = fmaf((float)hv[u], sc[u], sh[u]);
            hv[u] = (_Float16)(f > 0.f ? f : 0.f);
        }
        *(h8*)(x + v * 8) = hv;
    }
}

// ---------------------------------------------------------------------------
extern "C" void kernel_launch(void* const* d_in, const int* in_sizes, int n_in,
                              void* d_out, int out_size, void* d_ws, size_t ws_size,
                              hipStream_t stream)
{
    const float* feats = (const float*)d_in[0];
    const float* W0  = (const float*)d_in[1];
    const float* g0  = (const float*)d_in[2];
    const float* b0  = (const float*)d_in[3];
    const float* W1  = (const float*)d_in[4];
    const float* g1  = (const float*)d_in[5];
    const float* b1  = (const float*)d_in[6];
    const float* W2  = (const float*)d_in[7];
    const float* g2  = (const float*)d_in[8];
    const float* b2  = (const float*)d_in[9];
    const float* W2t = (const float*)d_in[10];
    const float* g2t = (const float*)d_in[11];
    const float* b2t = (const float*)d_in[12];
    const float* W1t = (const float*)d_in[13];
    const float* g1t = (const float*)d_in[14];
    const float* b1t = (const float*)d_in[15];
    const float* W0t = (const float*)d_in[16];
    const int* map0  = (const int*)d_in[17];
    const int* map1  = (const int*)d_in[18];
    const int* map2  = (const int*)d_in[19];
    const int* map2t = (const int*)d_in[20];
    const int* map1t = (const int*)d_in[21];
    const int* map0t = (const int*)d_in[22];

    const int N0 = in_sizes[0] / 16;
    const int N1 = in_sizes[18] / 27;
    const int N2 = in_sizes[19] / 27;

    const int Npad0 = (N0 + 15) & ~15;
    const int Npad1 = (N1 + 15) & ~15;

    float* ws = (float*)d_ws;
    float* sums  = ws;          // 704 floats of BN accumulators
    float* sums0 = sums;        // 2*32
    float* sums1 = sums + 64;   // 2*64
    float* sums2 = sums + 192;  // 2*128
    float* sums3 = sums + 448;  // 2*64
    float* sums4 = sums + 576;  // 2*64
    float* zrow  = sums + 704;  // 128 zeroed floats (fp32 & f16 zero rows)
    int*   gcnt  = (int*)(zrow + 128);  // 64 ints: 2x gcursor[9] regions
    _Float16* Wm0h = (_Float16*)(gcnt + 64);    // 27*2*32*8 f16 (paired MFMA)
    _Float16* Wh1  = Wm0h + 27 * 2 * 32 * 8;    // 27*32*64  (MFMA layout)
    _Float16* Wh2  = Wh1 + 27 * 32 * 64;        // 27*64*128  (MFMA layout)
    _Float16* Wh2t = Wh2 + 27 * 64 * 128;       // 27*128*64  (MFMA layout)
    _Float16* Wh1t = Wh2t + 27 * 128 * 64;      // 27*128*64  (MFMA layout)
    _Float16* y0 = Wh1t + 27 * 128 * 64;        // [N0,32]  s1
    _Float16* y1 = y0 + (size_t)N0 * 32;        // [N1,64]  s2
    _Float16* y2 = y1 + (size_t)N1 * 64;        // [N2,128] s4
    _Float16* y3 = y2 + (size_t)N2 * 128;       // [N1,64]  d2
    _Float16* y4 = y3 + (size_t)N1 * 64;        // [N0,64]  d1
    int* mapT = (int*)(y4 + (size_t)N0 * 64);   // [Nmax,32] transposed map
    int* orderA = mapT + (size_t)N0 * 32;       // [9*Npad1] block2_tr groups
    int* orderB = orderA + (size_t)9 * Npad1;   // [9*Npad0] block1_tr groups
    const _Float16* zrh = (const _Float16*)zrow;

    (void)hipMemsetAsync(sums, 0, (704 + 128 + 64) * sizeof(float), stream);
    (void)hipMemsetAsync(orderA, 0xFF,
                         (size_t)9 * (Npad1 + Npad0) * sizeof(int), stream);

    // weight transforms (tiny)
    wtrans_mf0<<<(27 * 2 * 32 + 255) / 256, 256, 0, stream>>>(W0, Wm0h);
    wtrans_mf<32, 64><<<(27 * 1 * 4 * 64 + 255) / 256, 256, 0, stream>>>(W1, Wh1);
    wtrans_mf<64, 128><<<(27 * 2 * 8 * 64 + 255) / 256, 256, 0, stream>>>(W2, Wh2);
    wtrans_mf<128, 64><<<(27 * 4 * 4 * 64 + 255) / 256, 256, 0, stream>>>(W2t, Wh2t);
    wtrans_mf<128, 64><<<(27 * 4 * 4 * 64 + 255) / 256, 256, 0, stream>>>(W1t, Wh1t);

    // block0: feats[N0,16] fp32 -> y0[N0,32] half. MFMA k-paired hi/lo.
    sconv_mf0<<<(N0 + 63) / 64, 256, 0, stream>>>(
        feats, Wm0h, map0, N0, y0, zrow);
    bn_reduce_v<32><<<512, 256, 0, stream>>>(y0, N0, sums0);
    bn_apply_v<32><<<1024, 256, 0, stream>>>(y0, N0, sums0, g0, b0);

    // block1: MFMA ungrouped, 32 rows/wave (was sconv_r1 1 row/wave + a
    // map_transpose pass -- both dropped)
    sconv_mf<32, 32, 64><<<(N1 + 127) / 128, 256, 0, stream>>>(
        y0, nullptr, Wh1, map1, N1, y1, zrh);
    bn_reduce_v<64><<<512, 256, 0, stream>>>(y1, N1, sums1);
    bn_apply_v<64><<<1024, 256, 0, stream>>>(y1, N1, sums1, g1, b1);

    // block2: MFMA ungrouped, 32 rows/wave
    sconv_mf<64, 64, 128><<<(N2 + 127) / 128, 256, 0, stream>>>(
        y1, nullptr, Wh2, map2, N2, y2, zrh);
    bn_reduce_v<128><<<512, 256, 0, stream>>>(y2, N2, sums2);
    bn_apply_v<128><<<1024, 256, 0, stream>>>(y2, N2, sums2, g2, b2);

    // block2_tr: parity-grouped MFMA, 32 rows/wave
    map_transpose_grp<<<(N1 + 255) / 256, 256, 0, stream>>>(
        map2t, N1, Npad1, mapT, gcnt, orderA);
    sconv_mf_g<128, 128, 64><<<(9 * Npad1 + 127) / 128, 256, 0, stream>>>(
        y2, nullptr, Wh2t, mapT, orderA, 9 * Npad1, N1, y3, zrh);
    bn_reduce_v<64><<<512, 256, 0, stream>>>(y3, N1, sums3);
    bn_apply_v<64><<<1024, 256, 0, stream>>>(y3, N1, sums3, g2t, b2t);

    // block1_tr: parity-grouped MFMA, 32 rows/wave, concat (y3[64] ++ y1[64])
    map_transpose_grp<<<(N0 + 255) / 256, 256, 0, stream>>>(
        map1t, N0, Npad0, mapT, gcnt + 32, orderB);
    sconv_mf_g<128, 64, 64><<<(9 * Npad0 + 127) / 128, 256, 0, stream>>>(
        y3, y1, Wh1t, mapT, orderB, 9 * Npad0, N0, y4, zrh);
    bn_reduce_v<64><<<512, 256, 0, stream>>>(y4, N0, sums4);
    bn_apply_v<64><<<1024, 256, 0, stream>>>(y4, N0, sums4, g1t, b1t);

    // block0_tr: gather conv (2-k pipelined, vectorized) -> out[N0,2] fp32
    sconv0t<<<(N0 + 7) / 8, 256, 0, stream>>>(y4, y0, W0t, map0t, N0,
                                              (float*)d_out, zrh);
}

// Round 12
// 630.336 us; speedup vs baseline: 1.3485x; 1.0517x over previous
//
#include <hip/hip_runtime.h>
#include <cstddef>
#include <cstdint>

#define BN_EPS 1e-5f

typedef float f2 __attribute__((ext_vector_type(2)));
typedef float f4 __attribute__((ext_vector_type(4)));
typedef float f32x4 __attribute__((ext_vector_type(4)));
typedef _Float16 h2 __attribute__((ext_vector_type(2)));
typedef _Float16 h8 __attribute__((ext_vector_type(8)));

// ---------------------------------------------------------------------------
// MFMA weight transform: W[27][CIN][COUT] fp32 -> B-fragment layout f16:
// Wm[((k*NT + t)*NC + ct)*64 + lane][8], h8 holds B[kk][co] with
// kk = t*32 + (lane>>4)*8 + u, co = ct*16 + (lane&15).
// ---------------------------------------------------------------------------
template<int CIN, int COUT>
__global__ __launch_bounds__(256)
void wtrans_mf(const float* __restrict__ W, _Float16* __restrict__ Wm)
{
    constexpr int NT = CIN / 32;
    constexpr int NC = COUT / 16;
    const int t = blockIdx.x * 256 + threadIdx.x;
    constexpr int TOTAL = 27 * NT * NC * 64;
    if (t >= TOTAL) return;
    const int lane = t & 63;
    int rest = t >> 6;
    const int ct = rest % NC; rest /= NC;
    const int tt = rest % NT;
    const int k  = rest / NT;
    const int cin0 = tt * 32 + (lane >> 4) * 8;
    const int co   = ct * 16 + (lane & 15);
    h8 v;
    #pragma unroll
    for (int u = 0; u < 8; ++u)
        v[u] = (_Float16)W[((size_t)k * CIN + cin0 + u) * COUT + co];
    *(h8*)(Wm + (size_t)t * 8) = v;
}

// ---------------------------------------------------------------------------
// conv0 MFMA weight transform (CIN=16, COUT=32, k-PAIRED):
// Wm0[((k*2 + s)*32 + co)*8 + u] = f16(W0[k][s*8+u][co]).
// ---------------------------------------------------------------------------
__global__ __launch_bounds__(256)
void wtrans_mf0(const float* __restrict__ W, _Float16* __restrict__ Wm0)
{
    const int t = blockIdx.x * 256 + threadIdx.x;
    constexpr int TOTAL = 27 * 2 * 32;
    if (t >= TOTAL) return;
    const int co = t % 32;
    const int s  = (t / 32) % 2;
    const int k  = t / 64;
    h8 v;
    #pragma unroll
    for (int u = 0; u < 8; ++u)
        v[u] = (_Float16)W[((size_t)k * 16 + s * 8 + u) * 32 + co];
    *(h8*)(Wm0 + (size_t)t * 8) = v;
}

// ---------------------------------------------------------------------------
// Map transpose + parity-class GROUPING, contention-free: LDS histogram ->
// 9 global atomics PER BLOCK -> LDS cursors. Class regions fixed at c*Npad
// in order[] (unfilled slots stay -1, pre-memset 0xFF). Perf heuristic only.
// ---------------------------------------------------------------------------
__global__ __launch_bounds__(256)
void map_transpose_grp(const int* __restrict__ map, int Nout, int Npad,
                       int* __restrict__ mapT, int* __restrict__ gcursor,
                       int* __restrict__ order)
{
    __shared__ int s[256][28];
    __shared__ int hist[9], basec[9], cur[9];
    const int tid  = threadIdx.x;
    const int base = blockIdx.x * 256;
    const int j    = base + tid;
    if (tid < 9) { hist[tid] = 0; cur[tid] = 0; }
    for (int k = 0; k < 27; ++k)
        s[tid][k] = (j < Nout) ? map[(size_t)k * Nout + j] : -1;
    __syncthreads();
    for (int i = tid; i < 256 * 32; i += 256) {
        const int r = i >> 5, c = i & 31;
        if (base + r < Nout)
            mapT[(size_t)(base + r) * 32 + c] = (c < 27) ? s[r][c] : -1;
    }
    int c9 = 8;
    if (j < Nout) {
        #pragma unroll 1
        for (int k = 0; k < 27; ++k) {
            if (s[tid][k] >= 0) {
                const int dz = k % 3, dy = (k / 3) % 3, dx = k / 9;
                c9 = ((dx != 1) << 2) | ((dy != 1) << 1) | (int)(dz != 1);
                break;
            }
        }
        atomicAdd(&hist[c9], 1);
    }
    __syncthreads();
    if (tid < 9 && hist[tid] > 0)
        basec[tid] = atomicAdd(&gcursor[tid], hist[tid]);
    __syncthreads();
    if (j < Nout) {
        const int lpos = atomicAdd(&cur[c9], 1);
        order[(size_t)c9 * Npad + basec[c9] + lpos] = j;
    }
}

// ---------------------------------------------------------------------------
// conv0 MFMA (CIN=16 fp32 in, COUT=32, k-PAIRED, compensated hi/lo).
// ---------------------------------------------------------------------------
__global__ __launch_bounds__(256)
void sconv_mf0(const float* __restrict__ x, const _Float16* __restrict__ Wm0,
               const int* __restrict__ map, int Nout,
               _Float16* __restrict__ out, const float* __restrict__ zrow)
{
    const int lane = threadIdx.x & 63;
    const int wave = threadIdx.x >> 6;
    const int row0 = (blockIdx.x * 4 + wave) * 16;

    __shared__ int smap[4][16][28];

    int mk[16];
    bool anyv = false;
    #pragma unroll
    for (int r = 0; r < 16; ++r) {
        const int j = row0 + r;
        mk[r] = (lane < 27 && j < Nout) ? map[(size_t)lane * Nout + j] : -1;
        anyv |= (mk[r] >= 0);
    }
    unsigned long long act = __ballot(anyv);

    if (lane < 27) {
        #pragma unroll
        for (int r = 0; r < 16; ++r)
            smap[wave][r][lane] = mk[r];
    }

    f32x4 accH[2], accL[2];
    #pragma unroll
    for (int c = 0; c < 2; ++c) {
        accH[c] = (f32x4){0.f, 0.f, 0.f, 0.f};
        accL[c] = (f32x4){0.f, 0.f, 0.f, 0.f};
    }

    const int rrow = lane & 15;   // A row / D col
    const int kseg = lane >> 4;
    const int half = kseg & 1;    // cin half: 0 -> 0..7, 1 -> 8..15
    const bool useK1 = (kseg < 2);

    while (act) {
        const int k1 = (int)__builtin_ctzll(act);
        act &= act - 1;
        int k2 = -1;
        if (act) {
            k2 = (int)__builtin_ctzll(act);
            act &= act - 1;
        }
        const int ks = useK1 ? k1 : k2;
        int m = -1;
        if (ks >= 0) m = smap[wave][rrow][ks];

        const float* px = (m >= 0) ? (x + (size_t)m * 16 + half * 8)
                                   : (zrow + half * 8);
        const f4 x0 = *(const f4*)px;
        const f4 x1 = *(const f4*)(px + 4);
        h8 aH, aL;
        #pragma unroll
        for (int u = 0; u < 4; ++u) {
            const float v0 = x0[u], v1 = x1[u];
            const _Float16 h0 = (_Float16)v0;
            const _Float16 h1 = (_Float16)v1;
            aH[u]     = h0;
            aH[u + 4] = h1;
            aL[u]     = (_Float16)((v0 - (float)h0) * 2048.f);
            aL[u + 4] = (_Float16)((v1 - (float)h1) * 2048.f);
        }

        const int ksafe = (ks >= 0) ? ks : 0;   // a==0 makes b irrelevant
        const _Float16* wb = Wm0 + ((size_t)(ksafe * 2 + half) * 32) * 8;
        #pragma unroll
        for (int c = 0; c < 2; ++c) {
            const h8 b = *(const h8*)(wb + (size_t)(c * 16 + rrow) * 8);
            accH[c] = __builtin_amdgcn_mfma_f32_16x16x32_f16(aH, b, accH[c], 0, 0, 0);
            accL[c] = __builtin_amdgcn_mfma_f32_16x16x32_f16(aL, b, accL[c], 0, 0, 0);
        }
    }

    #pragma unroll
    for (int c = 0; c < 2; ++c) {
        #pragma unroll
        for (int r = 0; r < 4; ++r) {
            const int j = row0 + kseg * 4 + r;
            if (j < Nout)
                out[(size_t)j * 32 + c * 16 + rrow] =
                    (_Float16)(accH[c][r] + accL[c][r] * (1.f / 2048.f));
        }
    }
}

// ---------------------------------------------------------------------------
// MFMA sparse conv (UNGROUPED, raw map): one wave = 32 rows = TWO 16-row
// MFMA tiles sharing one k-union and the SAME B fragments.
// Round-12 fix: prologue loads ALL 32 map values into REGISTERS first (all
// loads in flight, ~1 latency), THEN writes LDS. The round-8 merged loop
// interleaved each global load with its LDS write -> ~32 serial HBM round
// trips per wave (the 39k-cycle/wave stall behind MfmaUtil 4%).
// ---------------------------------------------------------------------------
template<int CIN, int CINA, int COUT>
__global__ __launch_bounds__(256)
void sconv_mf(const _Float16* __restrict__ xA, const _Float16* __restrict__ xB,
              const _Float16* __restrict__ Wm, const int* __restrict__ map,
              int Nout, _Float16* __restrict__ out,
              const _Float16* __restrict__ zrh)
{
    constexpr int CINB = CIN - CINA;
    constexpr int NT = CIN / 32;
    constexpr int NC = COUT / 16;
    static_assert(CINA % 32 == 0, "CINA must be a multiple of 32");
    const int lane = threadIdx.x & 63;
    const int wave = threadIdx.x >> 6;
    const int row0 = (blockIdx.x * 4 + wave) * 32;

    __shared__ int smap[4][32][28];

    // registers-first staging: pure-load loop, then LDS writes
    int mv[32];
    #pragma unroll
    for (int r = 0; r < 32; ++r) {
        const int j = row0 + r;
        mv[r] = (lane < 27 && j < Nout) ? map[(size_t)lane * Nout + j] : -1;
    }
    bool anyv = false;
    #pragma unroll
    for (int r = 0; r < 32; ++r) {
        if (lane < 27) smap[wave][r][lane] = mv[r];
        anyv |= (mv[r] >= 0);
    }
    unsigned long long act = __ballot(anyv) & 0x7FFFFFFull;

    f32x4 acc[2][NC];
    #pragma unroll
    for (int tt = 0; tt < 2; ++tt)
        #pragma unroll
        for (int c = 0; c < NC; ++c) acc[tt][c] = (f32x4){0.f, 0.f, 0.f, 0.f};

    const int rrow = lane & 15;
    const int kseg = lane >> 4;

    auto loada = [&](int k, h8 a[2][NT]) {
        #pragma unroll
        for (int tt = 0; tt < 2; ++tt) {
            const int m = smap[wave][tt * 16 + rrow][k];
            #pragma unroll
            for (int t = 0; t < NT; ++t) {
                const int cin0 = t * 32 + kseg * 8;
                const _Float16* pa;
                if (m >= 0) {
                    if (CINB > 0 && t * 32 >= CINA)
                        pa = xB + (size_t)m * CINB + (cin0 - CINA);
                    else
                        pa = xA + (size_t)m * CINA + cin0;
                } else {
                    pa = zrh;
                }
                a[tt][t] = *(const h8*)pa;
            }
        }
    };
    auto compute = [&](int k, h8 a[2][NT]) {
        const _Float16* Wk = Wm + ((size_t)k * NT * NC * 64 + lane) * 8;
        #pragma unroll
        for (int t = 0; t < NT; ++t) {
            #pragma unroll
            for (int c = 0; c < NC; ++c) {
                const h8 b = *(const h8*)(Wk + (size_t)(t * NC + c) * 64 * 8);
                acc[0][c] = __builtin_amdgcn_mfma_f32_16x16x32_f16(a[0][t], b, acc[0][c], 0, 0, 0);
                acc[1][c] = __builtin_amdgcn_mfma_f32_16x16x32_f16(a[1][t], b, acc[1][c], 0, 0, 0);
            }
        }
    };

    h8 aC[2][NT], aN[2][NT];
    int kC = -1;
    if (act) {
        kC = (int)__builtin_ctzll(act);
        act &= act - 1;
        loada(kC, aC);
    }
    while (kC >= 0) {
        int kN = -1;
        if (act) {
            kN = (int)__builtin_ctzll(act);
            act &= act - 1;
            loada(kN, aN);
        }
        compute(kC, aC);
        #pragma unroll
        for (int tt = 0; tt < 2; ++tt)
            #pragma unroll
            for (int t = 0; t < NT; ++t) aC[tt][t] = aN[tt][t];
        kC = kN;
    }

    #pragma unroll
    for (int tt = 0; tt < 2; ++tt) {
        #pragma unroll
        for (int c = 0; c < NC; ++c) {
            #pragma unroll
            for (int r = 0; r < 4; ++r) {
                const int j = row0 + tt * 16 + kseg * 4 + r;
                if (j < Nout)
                    out[(size_t)j * COUT + c * 16 + rrow] = (_Float16)acc[tt][c][r];
            }
        }
    }
}

// ---------------------------------------------------------------------------
// MFMA sparse conv (GROUPED): 32 order slots/wave, two 16-row MFMA tiles.
// Round-12 fix: prologue row indices come from __shfl(jreg, r) (register
// broadcast, no LDS dependency), mapT values load into REGISTERS (all 32
// loads in flight), THEN LDS. Dead waves exit before any staging.
// ---------------------------------------------------------------------------
template<int CIN, int CINA, int COUT>
__global__ __launch_bounds__(256)
void sconv_mf_g(const _Float16* __restrict__ xA, const _Float16* __restrict__ xB,
                const _Float16* __restrict__ Wm, const int* __restrict__ mapT,
                const int* __restrict__ order, int NTOT, int Nout,
                _Float16* __restrict__ out, const _Float16* __restrict__ zrh)
{
    constexpr int CINB = CIN - CINA;
    constexpr int NT = CIN / 32;
    constexpr int NC = COUT / 16;
    static_assert(CINA % 32 == 0, "CINA must be a multiple of 32");
    const int lane = threadIdx.x & 63;
    const int wave = threadIdx.x >> 6;
    const int wrow0 = (blockIdx.x * 4 + wave) * 32;

    __shared__ int sjr[4][32];
    __shared__ int smap[4][32][28];

    int jreg = -1;
    if (lane < 32) {
        const int idx = wrow0 + lane;
        if (idx < NTOT) jreg = order[idx];
    }
    if (!__ballot(jreg >= 0)) return;     // dead wave: region tail padding
    if (lane < 32) sjr[wave][lane] = jreg;   // epilogue indexing only

    // registers-first staging via shfl-broadcast row ids
    int mv[32];
    #pragma unroll
    for (int r = 0; r < 32; ++r) {
        const int jr = __shfl(jreg, r);
        mv[r] = (jr >= 0 && lane < 27) ? mapT[(size_t)jr * 32 + lane] : -1;
    }
    bool anyv = false;
    #pragma unroll
    for (int r = 0; r < 32; ++r) {
        if (lane < 27) smap[wave][r][lane] = mv[r];
        anyv |= (mv[r] >= 0);
    }
    unsigned long long act = __ballot(anyv) & 0x7FFFFFFull;

    f32x4 acc[2][NC];
    #pragma unroll
    for (int tt = 0; tt < 2; ++tt)
        #pragma unroll
        for (int c = 0; c < NC; ++c) acc[tt][c] = (f32x4){0.f, 0.f, 0.f, 0.f};

    const int rrow = lane & 15;
    const int kseg = lane >> 4;

    auto loada = [&](int k, h8 a[2][NT]) {
        #pragma unroll
        for (int tt = 0; tt < 2; ++tt) {
            const int m = smap[wave][tt * 16 + rrow][k];
            #pragma unroll
            for (int t = 0; t < NT; ++t) {
                const int cin0 = t * 32 + kseg * 8;
                const _Float16* pa;
                if (m >= 0) {
                    if (CINB > 0 && t * 32 >= CINA)
                        pa = xB + (size_t)m * CINB + (cin0 - CINA);
                    else
                        pa = xA + (size_t)m * CINA + cin0;
                } else {
                    pa = zrh;
                }
                a[tt][t] = *(const h8*)pa;
            }
        }
    };
    auto compute = [&](int k, h8 a[2][NT]) {
        const _Float16* Wk = Wm + ((size_t)k * NT * NC * 64 + lane) * 8;
        #pragma unroll
        for (int t = 0; t < NT; ++t) {
            #pragma unroll
            for (int c = 0; c < NC; ++c) {
                const h8 b = *(const h8*)(Wk + (size_t)(t * NC + c) * 64 * 8);
                acc[0][c] = __builtin_amdgcn_mfma_f32_16x16x32_f16(a[0][t], b, acc[0][c], 0, 0, 0);
                acc[1][c] = __builtin_amdgcn_mfma_f32_16x16x32_f16(a[1][t], b, acc[1][c], 0, 0, 0);
            }
        }
    };

    h8 aC[2][NT], aN[2][NT];
    int kC = -1;
    if (act) {
        kC = (int)__builtin_ctzll(act);
        act &= act - 1;
        loada(kC, aC);
    }
    while (kC >= 0) {
        int kN = -1;
        if (act) {
            kN = (int)__builtin_ctzll(act);
            act &= act - 1;
            loada(kN, aN);
        }
        compute(kC, aC);
        #pragma unroll
        for (int tt = 0; tt < 2; ++tt)
            #pragma unroll
            for (int t = 0; t < NT; ++t) aC[tt][t] = aN[tt][t];
        kC = kN;
    }

    #pragma unroll
    for (int tt = 0; tt < 2; ++tt) {
        #pragma unroll
        for (int c = 0; c < NC; ++c) {
            #pragma unroll
            for (int r = 0; r < 4; ++r) {
                const int j = sjr[wave][tt * 16 + kseg * 4 + r];
                if (j >= 0)
                    out[(size_t)j * COUT + c * 16 + rrow] = (_Float16)acc[tt][c][r];
            }
        }
    }
}

// ---------------------------------------------------------------------------
// conv0t GATHER: 2-k-per-iteration pipeline + vectorized loads.
// ---------------------------------------------------------------------------
__global__ __launch_bounds__(256)
void sconv0t(const _Float16* __restrict__ d1, const _Float16* __restrict__ s1,
             const float* __restrict__ W /*[27,96,2]*/,
             const int* __restrict__ map, int N, float* __restrict__ out,
             const _Float16* __restrict__ zrh)
{
    const int tid  = threadIdx.x;
    const int lane = tid & 63;
    const int l32  = tid & 31;
    const int j    = blockIdx.x * 8 + (tid >> 5);

    int mk = (l32 < 27 && j < N) ? map[(size_t)l32 * N + j] : -1;
    const unsigned long long bal = __ballot(mk >= 0);
    unsigned int act = (unsigned int)((bal | (bal >> 32)) & 0x7FFFFFFu);

    float a0 = 0.f, a1 = 0.f;
    while (act) {
        const int k1 = (int)__builtin_ctz(act);
        act &= act - 1;
        int k2 = -1;
        if (act) { k2 = (int)__builtin_ctz(act); act &= act - 1; }
        const int k2s = (k2 >= 0) ? k2 : k1;

        const int m1 = __shfl(mk, (lane & 32) + k1);
        int m2 = __shfl(mk, (lane & 32) + k2s);
        if (k2 < 0) m2 = -1;

        // issue ALL gathers before any FMA
        const _Float16* p1a = (m1 >= 0) ? (d1 + (size_t)m1 * 64) : zrh;
        const _Float16* p1b = (m1 >= 0) ? (s1 + (size_t)m1 * 32) : zrh;
        const _Float16* p2a = (m2 >= 0) ? (d1 + (size_t)m2 * 64) : zrh;
        const _Float16* p2b = (m2 >= 0) ? (s1 + (size_t)m2 * 32) : zrh;
        const h2 xa1 = *(const h2*)(p1a + 2 * l32);
        const float xs1 = (float)p1b[l32];
        const h2 xa2 = *(const h2*)(p2a + 2 * l32);
        const float xs2 = (float)p2b[l32];

        const f4 wa1 = *(const f4*)(W + (size_t)k1 * 192 + 4 * l32);
        const f2 ws1 = *(const f2*)(W + (size_t)k1 * 192 + 128 + 2 * l32);
        const f4 wa2 = *(const f4*)(W + (size_t)k2s * 192 + 4 * l32);
        const f2 ws2 = *(const f2*)(W + (size_t)k2s * 192 + 128 + 2 * l32);

        a0 = fmaf((float)xa1[0], wa1[0], a0);
        a1 = fmaf((float)xa1[0], wa1[1], a1);
        a0 = fmaf((float)xa1[1], wa1[2], a0);
        a1 = fmaf((float)xa1[1], wa1[3], a1);
        a0 = fmaf(xs1, ws1[0], a0);
        a1 = fmaf(xs1, ws1[1], a1);

        a0 = fmaf((float)xa2[0], wa2[0], a0);
        a1 = fmaf((float)xa2[0], wa2[1], a1);
        a0 = fmaf((float)xa2[1], wa2[2], a0);
        a1 = fmaf((float)xa2[1], wa2[3], a1);
        a0 = fmaf(xs2, ws2[0], a0);
        a1 = fmaf(xs2, ws2[1], a1);
    }
    #pragma unroll
    for (int off = 1; off < 32; off <<= 1) {
        a0 += __shfl_xor(a0, off, 32);
        a1 += __shfl_xor(a1, off, 32);
    }
    if (l32 == 0 && j < N) {
        out[(size_t)j * 2 + 0] = a0;
        out[(size_t)j * 2 + 1] = a1;
    }
}

// ---------------------------------------------------------------------------
// BN pass 1, VECTORIZED: one h8 (8 channels) per thread per step; fp32
// 8-wide partials on fixed channels; phase-preserving butterfly; LDS; one
// atomic per channel per block.
// ---------------------------------------------------------------------------
template<int C>
__global__ __launch_bounds__(256)
void bn_reduce_v(const _Float16* __restrict__ x, int N,
                 float* __restrict__ sums)
{
    constexpr int CV = C / 8;   // h8 vectors per row (4, 8, or 16)
    const int tid  = threadIdx.x;
    const int lane = tid & 63;
    const int wave = tid >> 6;
    const size_t total  = (size_t)N * CV;
    const size_t stride = (size_t)gridDim.x * 256;   // multiple of CV
    const size_t gid    = (size_t)blockIdx.x * 256 + tid;

    float s[8], s2[8];
    #pragma unroll
    for (int u = 0; u < 8; ++u) { s[u] = 0.f; s2[u] = 0.f; }

    for (size_t v = gid; v < total; v += stride) {
        const h8 hv = *(const h8*)(x + v * 8);
        #pragma unroll
        for (int u = 0; u < 8; ++u) {
            const float f = (float)hv[u];
            s[u] += f;
            s2[u] += f * f;
        }
    }

    #pragma unroll
    for (int off = CV; off < 64; off <<= 1) {
        #pragma unroll
        for (int u = 0; u < 8; ++u) {
            s[u]  += __shfl_xor(s[u], off);
            s2[u] += __shfl_xor(s2[u], off);
        }
    }

    __shared__ float shs[4][16][8];
    __shared__ float shq[4][16][8];
    if (lane < CV) {
        #pragma unroll
        for (int u = 0; u < 8; ++u) {
            shs[wave][lane][u] = s[u];
            shq[wave][lane][u] = s2[u];
        }
    }
    __syncthreads();
    if (tid < C) {
        const int ph = tid >> 3, u = tid & 7;
        float ts = 0.f, tq = 0.f;
        #pragma unroll
        for (int w = 0; w < 4; ++w) {
            ts += shs[w][ph][u];
            tq += shq[w][ph][u];
        }
        atomicAdd(&sums[tid], ts);
        atomicAdd(&sums[C + tid], tq);
    }
}

// ---------------------------------------------------------------------------
// BN pass 2, VECTORIZED: h8 load -> 8x fma/relu -> h8 store.
// ---------------------------------------------------------------------------
template<int C>
__global__ __launch_bounds__(256)
void bn_apply_v(_Float16* __restrict__ x, int N,
                const float* __restrict__ sums,
                const float* __restrict__ g, const float* __restrict__ b)
{
    constexpr int CV = C / 8;
    const size_t total  = (size_t)N * CV;
    const size_t stride = (size_t)gridDim.x * 256;   // multiple of CV
    const size_t gid    = (size_t)blockIdx.x * 256 + threadIdx.x;
    const int phase = (int)(gid % CV);

    const float invN = 1.0f / (float)N;
    float sc[8], sh[8];
    #pragma unroll
    for (int u = 0; u < 8; ++u) {
        const int c = phase * 8 + u;
        const float mean = sums[c] * invN;
        float var = sums[C + c] * invN - mean * mean;
        var = fmaxf(var, 0.f);
        sc[u] = g[c] * rsqrtf(var + BN_EPS);
        sh[u] = b[c] - mean * sc[u];
    }

    for (size_t v = gid; v < total; v += stride) {
        h8 hv = *(h8*)(x + v * 8);
        #pragma unroll
        for (int u = 0; u < 8; ++u) {
            const float f = fmaf((float)hv[u], sc[u], sh[u]);
            hv[u] = (_Float16)(f > 0.f ? f : 0.f);
        }
        *(h8*)(x + v * 8) = hv;
    }
}

// ---------------------------------------------------------------------------
extern "C" void kernel_launch(void* const* d_in, const int* in_sizes, int n_in,
                              void* d_out, int out_size, void* d_ws, size_t ws_size,
                              hipStream_t stream)
{
    const float* feats = (const float*)d_in[0];
    const float* W0  = (const float*)d_in[1];
    const float* g0  = (const float*)d_in[2];
    const float* b0  = (const float*)d_in[3];
    const float* W1  = (const float*)d_in[4];
    const float* g1  = (const float*)d_in[5];
    const float* b1  = (const float*)d_in[6];
    const float* W2  = (const float*)d_in[7];
    const float* g2  = (const float*)d_in[8];
    const float* b2  = (const float*)d_in[9];
    const float* W2t = (const float*)d_in[10];
    const float* g2t = (const float*)d_in[11];
    const float* b2t = (const float*)d_in[12];
    const float* W1t = (const float*)d_in[13];
    const float* g1t = (const float*)d_in[14];
    const float* b1t = (const float*)d_in[15];
    const float* W0t = (const float*)d_in[16];
    const int* map0  = (const int*)d_in[17];
    const int* map1  = (const int*)d_in[18];
    const int* map2  = (const int*)d_in[19];
    const int* map2t = (const int*)d_in[20];
    const int* map1t = (const int*)d_in[21];
    const int* map0t = (const int*)d_in[22];

    const int N0 = in_sizes[0] / 16;
    const int N1 = in_sizes[18] / 27;
    const int N2 = in_sizes[19] / 27;

    const int Npad0 = (N0 + 15) & ~15;
    const int Npad1 = (N1 + 15) & ~15;

    float* ws = (float*)d_ws;
    float* sums  = ws;          // 704 floats of BN accumulators
    float* sums0 = sums;        // 2*32
    float* sums1 = sums + 64;   // 2*64
    float* sums2 = sums + 192;  // 2*128
    float* sums3 = sums + 448;  // 2*64
    float* sums4 = sums + 576;  // 2*64
    float* zrow  = sums + 704;  // 128 zeroed floats (fp32 & f16 zero rows)
    int*   gcnt  = (int*)(zrow + 128);  // 64 ints: 2x gcursor[9] regions
    _Float16* Wm0h = (_Float16*)(gcnt + 64);    // 27*2*32*8 f16 (paired MFMA)
    _Float16* Wh1  = Wm0h + 27 * 2 * 32 * 8;    // 27*32*64  (MFMA layout)
    _Float16* Wh2  = Wh1 + 27 * 32 * 64;        // 27*64*128  (MFMA layout)
    _Float16* Wh2t = Wh2 + 27 * 64 * 128;       // 27*128*64  (MFMA layout)
    _Float16* Wh1t = Wh2t + 27 * 128 * 64;      // 27*128*64  (MFMA layout)
    _Float16* y0 = Wh1t + 27 * 128 * 64;        // [N0,32]  s1
    _Float16* y1 = y0 + (size_t)N0 * 32;        // [N1,64]  s2
    _Float16* y2 = y1 + (size_t)N1 * 64;        // [N2,128] s4
    _Float16* y3 = y2 + (size_t)N2 * 128;       // [N1,64]  d2
    _Float16* y4 = y3 + (size_t)N1 * 64;        // [N0,64]  d1
    int* mapT = (int*)(y4 + (size_t)N0 * 64);   // [Nmax,32] transposed map
    int* orderA = mapT + (size_t)N0 * 32;       // [9*Npad1] block2_tr groups
    int* orderB = orderA + (size_t)9 * Npad1;   // [9*Npad0] block1_tr groups
    const _Float16* zrh = (const _Float16*)zrow;

    (void)hipMemsetAsync(sums, 0, (704 + 128 + 64) * sizeof(float), stream);
    (void)hipMemsetAsync(orderA, 0xFF,
                         (size_t)9 * (Npad1 + Npad0) * sizeof(int), stream);

    // weight transforms (tiny)
    wtrans_mf0<<<(27 * 2 * 32 + 255) / 256, 256, 0, stream>>>(W0, Wm0h);
    wtrans_mf<32, 64><<<(27 * 1 * 4 * 64 + 255) / 256, 256, 0, stream>>>(W1, Wh1);
    wtrans_mf<64, 128><<<(27 * 2 * 8 * 64 + 255) / 256, 256, 0, stream>>>(W2, Wh2);
    wtrans_mf<128, 64><<<(27 * 4 * 4 * 64 + 255) / 256, 256, 0, stream>>>(W2t, Wh2t);
    wtrans_mf<128, 64><<<(27 * 4 * 4 * 64 + 255) / 256, 256, 0, stream>>>(W1t, Wh1t);

    // block0: feats[N0,16] fp32 -> y0[N0,32] half. MFMA k-paired hi/lo.
    sconv_mf0<<<(N0 + 63) / 64, 256, 0, stream>>>(
        feats, Wm0h, map0, N0, y0, zrow);
    bn_reduce_v<32><<<512, 256, 0, stream>>>(y0, N0, sums0);
    bn_apply_v<32><<<1024, 256, 0, stream>>>(y0, N0, sums0, g0, b0);

    // block1: MFMA ungrouped, 32 rows/wave
    sconv_mf<32, 32, 64><<<(N1 + 127) / 128, 256, 0, stream>>>(
        y0, nullptr, Wh1, map1, N1, y1, zrh);
    bn_reduce_v<64><<<512, 256, 0, stream>>>(y1, N1, sums1);
    bn_apply_v<64><<<1024, 256, 0, stream>>>(y1, N1, sums1, g1, b1);

    // block2: MFMA ungrouped, 32 rows/wave
    sconv_mf<64, 64, 128><<<(N2 + 127) / 128, 256, 0, stream>>>(
        y1, nullptr, Wh2, map2, N2, y2, zrh);
    bn_reduce_v<128><<<512, 256, 0, stream>>>(y2, N2, sums2);
    bn_apply_v<128><<<1024, 256, 0, stream>>>(y2, N2, sums2, g2, b2);

    // block2_tr: parity-grouped MFMA, 32 rows/wave
    map_transpose_grp<<<(N1 + 255) / 256, 256, 0, stream>>>(
        map2t, N1, Npad1, mapT, gcnt, orderA);
    sconv_mf_g<128, 128, 64><<<(9 * Npad1 + 127) / 128, 256, 0, stream>>>(
        y2, nullptr, Wh2t, mapT, orderA, 9 * Npad1, N1, y3, zrh);
    bn_reduce_v<64><<<512, 256, 0, stream>>>(y3, N1, sums3);
    bn_apply_v<64><<<1024, 256, 0, stream>>>(y3, N1, sums3, g2t, b2t);

    // block1_tr: parity-grouped MFMA, 32 rows/wave, concat (y3[64] ++ y1[64])
    map_transpose_grp<<<(N0 + 255) / 256, 256, 0, stream>>>(
        map1t, N0, Npad0, mapT, gcnt + 32, orderB);
    sconv_mf_g<128, 64, 64><<<(9 * Npad0 + 127) / 128, 256, 0, stream>>>(
        y3, y1, Wh1t, mapT, orderB, 9 * Npad0, N0, y4, zrh);
    bn_reduce_v<64><<<512, 256, 0, stream>>>(y4, N0, sums4);
    bn_apply_v<64><<<1024, 256, 0, stream>>>(y4, N0, sums4, g1t, b1t);

    // block0_tr: gather conv (2-k pipelined, vectorized) -> out[N0,2] fp32
    sconv0t<<<(N0 + 7) / 8, 256, 0, stream>>>(y4, y0, W0t, map0t, N0,
                                              (float*)d_out, zrh);
}